// Round 1
// baseline (5216.112 us; speedup 1.0000x reference)
//
#include <hip/hip_runtime.h>

typedef unsigned short u16;
typedef __attribute__((ext_vector_type(8))) short bfrag;   // 8 bf16 in 4 VGPRs
typedef __attribute__((ext_vector_type(4))) float facc;    // MFMA accumulator

// ---------- fp32 -> bf16 split helpers ----------
__device__ __forceinline__ u16 f2bf(float x) {
  unsigned u = __float_as_uint(x);
  u += 0x7fffu + ((u >> 16) & 1u);     // round-to-nearest-even
  return (u16)(u >> 16);
}
__device__ __forceinline__ float bf2f(u16 h) {
  return __uint_as_float(((unsigned)h) << 16);
}
__device__ __forceinline__ void splitbf(float x, u16 &hi, u16 &lo) {
  u16 h = f2bf(x);
  hi = h;
  lo = f2bf(x - bf2f(h));
}

// ---------- embedding: h = tok_emb[x] + pos_emb ----------
__global__ void embed_kernel(const int* __restrict__ x, const float* __restrict__ tok,
                             const float* __restrict__ pos, float* __restrict__ h) {
  int i = blockIdx.x * 256 + threadIdx.x;      // over 8192*192 float4
  int m = i / 192;
  int d4 = i % 192;
  int v = x[m];
  float4 t = ((const float4*)tok)[(long)v * 192 + d4];
  float4 p = ((const float4*)pos)[(long)(m & 1023) * 192 + d4];
  float4 r;
  r.x = t.x + p.x; r.y = t.y + p.y; r.z = t.z + p.z; r.w = t.w + p.w;
  ((float4*)h)[i] = r;
}

// ---------- plain split convert (no transpose), float4-granular ----------
__global__ void split_kernel(const float* __restrict__ in, u16* __restrict__ ohi,
                             u16* __restrict__ olo, int n4) {
  int i = blockIdx.x * 256 + threadIdx.x;
  if (i >= n4) return;
  float4 v = ((const float4*)in)[i];
  ushort4 h4, l4;
  splitbf(v.x, h4.x, l4.x);
  splitbf(v.y, h4.y, l4.y);
  splitbf(v.z, h4.z, l4.z);
  splitbf(v.w, h4.w, l4.w);
  ((ushort4*)ohi)[i] = h4;
  ((ushort4*)olo)[i] = l4;
}

// ---------- transpose + split: W[K][N] fp32 -> WT_hi/lo [N][K] bf16 ----------
__global__ __launch_bounds__(256)
void tsplit_kernel(const float* __restrict__ W, u16* __restrict__ ohi,
                   u16* __restrict__ olo, int K, int N) {
  __shared__ float tile[32][33];
  const int tx = threadIdx.x & 31, ty = threadIdx.x >> 5;
  const long n0 = (long)blockIdx.x * 32, k0 = (long)blockIdx.y * 32;
#pragma unroll
  for (int r = 0; r < 4; ++r) {
    int kk = ty + r * 8;
    tile[kk][tx] = W[(k0 + kk) * N + n0 + tx];
  }
  __syncthreads();
#pragma unroll
  for (int r = 0; r < 4; ++r) {
    int nn = ty + r * 8;
    float v = tile[tx][nn];
    u16 hi, lo;
    splitbf(v, hi, lo);
    long off = (n0 + nn) * K + k0 + tx;
    ohi[off] = hi;
    olo[off] = lo;
  }
}

// ---------- LayerNorm (D=768) + split output ----------
__global__ __launch_bounds__(256)
void ln_split_kernel(const float* __restrict__ x, const float* __restrict__ gam,
                     const float* __restrict__ bet, u16* __restrict__ ohi,
                     u16* __restrict__ olo) {
  const int row = blockIdx.x, tid = threadIdx.x;
  const float* xp = x + (long)row * 768;
  float v0 = xp[tid], v1 = xp[tid + 256], v2 = xp[tid + 512];
  float s = v0 + v1 + v2;
  float q = v0 * v0 + v1 * v1 + v2 * v2;
#pragma unroll
  for (int d = 32; d > 0; d >>= 1) {
    s += __shfl_xor(s, d);
    q += __shfl_xor(q, d);
  }
  __shared__ float red[8];
  const int wave = tid >> 6, lane = tid & 63;
  if (lane == 0) { red[wave] = s; red[4 + wave] = q; }
  __syncthreads();
  s = red[0] + red[1] + red[2] + red[3];
  q = red[4] + red[5] + red[6] + red[7];
  const float mu = s * (1.0f / 768.0f);
  const float var = q * (1.0f / 768.0f) - mu * mu;
  const float rstd = rsqrtf(var + 1e-5f);
  const long base = (long)row * 768;
  u16 hi, lo;
  float y0 = (v0 - mu) * rstd * gam[tid] + bet[tid];
  splitbf(y0, hi, lo); ohi[base + tid] = hi; olo[base + tid] = lo;
  float y1 = (v1 - mu) * rstd * gam[tid + 256] + bet[tid + 256];
  splitbf(y1, hi, lo); ohi[base + tid + 256] = hi; olo[base + tid + 256] = lo;
  float y2 = (v2 - mu) * rstd * gam[tid + 512] + bet[tid + 512];
  splitbf(y2, hi, lo); ohi[base + tid + 512] = hi; olo[base + tid + 512] = lo;
}

// ---------- split-bf16 GEMM, B^T layout: C[M][N] = A[M][K] @ B(BT[N][K]) ----------
// 128x128 tile, BK=64, 4 waves (2x2 of 64x64), 3-term split MFMA.
// EPI: 0 = +bias -> f32 ; 1 = +bias+res -> f32 ; 2 = +bias, GELU -> split bf16 ; 3 = plain -> f32
template <int EPI>
__global__ __launch_bounds__(256, 2)
void gemm_bt(const u16* __restrict__ Ahi, const u16* __restrict__ Alo,
             const u16* __restrict__ Bhi, const u16* __restrict__ Blo,
             int M, int N, int K, const float* __restrict__ bias,
             const float* res, float* outf, u16* outhi, u16* outlo) {
  __shared__ u16 lds[4 * 128 * 64];          // 64 KB: Ahi, Alo, Bhi, Blo tiles
  u16* sAh = lds;
  u16* sAl = lds + 8192;
  u16* sBh = lds + 16384;
  u16* sBl = lds + 24576;

  const int tid = threadIdx.x;
  const int lane = tid & 63, wave = tid >> 6;
  const int g = lane >> 4, c = lane & 15;
  const int nb = N >> 7;
  const int mt = blockIdx.x / nb, nt = blockIdx.x % nb;
  const long m0 = (long)mt << 7, n0 = (long)nt << 7;
  const int wm = (wave >> 1) << 6, wn = (wave & 1) << 6;

  facc acc[4][4] = {};

  int arow[4], brow[4];
#pragma unroll
  for (int i = 0; i < 4; ++i) {
    arow[i] = wm + i * 16 + c;
    brow[i] = wn + i * 16 + c;
  }

  const int nkt = K >> 6;
  for (int kt = 0; kt < nkt; ++kt) {
    __syncthreads();
    {
      const long kcol = (long)kt * 64;
#pragma unroll
      for (int i = 0; i < 4; ++i) {
        int chunk = i * 256 + tid;                       // 0..1023
        int row = chunk >> 3;
        int slot = chunk & 7;
        int dst = (chunk * 16) ^ ((row & 7) << 4);       // swizzled byte offset in tile
        const long ga = (m0 + row) * (long)K + kcol + slot * 8;
        const long gb = (n0 + row) * (long)K + kcol + slot * 8;
        *(int4*)((char*)sAh + dst) = *(const int4*)(Ahi + ga);
        *(int4*)((char*)sAl + dst) = *(const int4*)(Alo + ga);
        *(int4*)((char*)sBh + dst) = *(const int4*)(Bhi + gb);
        *(int4*)((char*)sBl + dst) = *(const int4*)(Blo + gb);
      }
    }
    __syncthreads();
#pragma unroll
    for (int ks = 0; ks < 2; ++ks) {
      const int kb = (ks * 32 + g * 8) * 2;              // byte offset of this lane's k-slice
      bfrag ah[4], al[4], bh[4], bl[4];
#pragma unroll
      for (int i = 0; i < 4; ++i) {
        int ab = arow[i] * 128 + (kb ^ ((arow[i] & 7) << 4));
        ah[i] = *(const bfrag*)((const char*)sAh + ab);
        al[i] = *(const bfrag*)((const char*)sAl + ab);
        int bb = brow[i] * 128 + (kb ^ ((brow[i] & 7) << 4));
        bh[i] = *(const bfrag*)((const char*)sBh + bb);
        bl[i] = *(const bfrag*)((const char*)sBl + bb);
      }
#pragma unroll
      for (int mi = 0; mi < 4; ++mi)
#pragma unroll
        for (int ni = 0; ni < 4; ++ni) {
          acc[mi][ni] = __builtin_amdgcn_mfma_f32_16x16x32_bf16(ah[mi], bh[ni], acc[mi][ni], 0, 0, 0);
          acc[mi][ni] = __builtin_amdgcn_mfma_f32_16x16x32_bf16(ah[mi], bl[ni], acc[mi][ni], 0, 0, 0);
          acc[mi][ni] = __builtin_amdgcn_mfma_f32_16x16x32_bf16(al[mi], bh[ni], acc[mi][ni], 0, 0, 0);
        }
    }
  }

#pragma unroll
  for (int mi = 0; mi < 4; ++mi)
#pragma unroll
    for (int ni = 0; ni < 4; ++ni)
#pragma unroll
      for (int r = 0; r < 4; ++r) {
        long row = m0 + wm + mi * 16 + g * 4 + r;        // C/D: col=lane&15, row=(lane>>4)*4+reg
        long col = n0 + wn + ni * 16 + c;
        float v = acc[mi][ni][r];
        if (EPI != 3) v += bias[col];
        if (EPI == 1) v += res[row * N + col];
        if (EPI == 2) {
          v = 0.5f * v * (1.0f + erff(v * 0.70710678118654752f));
          u16 hi, lo;
          splitbf(v, hi, lo);
          outhi[row * N + col] = hi;
          outlo[row * N + col] = lo;
        } else {
          outf[row * N + col] = v;
        }
      }
}

// ---------- fused flash attention: bf16 MFMA, fp32 online softmax ----------
// grid: (B*H)*16 blocks, 256 threads (4 waves); wave owns 16 q rows; KV blocks of 64.
__global__ __launch_bounds__(256, 2)
void attn_kernel(const float* __restrict__ qkv, u16* __restrict__ ohi,
                 u16* __restrict__ olo) {
  __shared__ u16 sK[64 * 64];        // [k][d] swizzled
  __shared__ u16 sV[64 * 64];        // V^T: [d][k] swizzled
  __shared__ u16 sP[4][16 * 64];     // per-wave P tile [q][k] swizzled
  const int tid = threadIdx.x;
  const int lane = tid & 63, wave = tid >> 6;
  const int g = lane >> 4, c = lane & 15;
  const int bh = blockIdx.x >> 4, qt = blockIdx.x & 15;
  const int b = bh / 12, hh = bh % 12;
  const float* base = qkv + (long)b * 1024 * 2304 + hh * 64;

  // Q fragments in registers (A operand): row = c, k(d) = ss*32 + g*8 + j
  bfrag qa[2];
  {
    const int qrow = qt * 64 + wave * 16 + c;
    const float* qp = base + (long)qrow * 2304;
#pragma unroll
    for (int ss = 0; ss < 2; ++ss) {
      float4 f0 = *(const float4*)(qp + ss * 32 + g * 8);
      float4 f1 = *(const float4*)(qp + ss * 32 + g * 8 + 4);
      bfrag t;
      t[0] = (short)f2bf(f0.x); t[1] = (short)f2bf(f0.y);
      t[2] = (short)f2bf(f0.z); t[3] = (short)f2bf(f0.w);
      t[4] = (short)f2bf(f1.x); t[5] = (short)f2bf(f1.y);
      t[6] = (short)f2bf(f1.z); t[7] = (short)f2bf(f1.w);
      qa[ss] = t;
    }
  }

  facc o[4] = {};
  float m[4], l[4];
#pragma unroll
  for (int r = 0; r < 4; ++r) { m[r] = -1e30f; l[r] = 0.0f; }

  const int kr = tid >> 2;
  const int cc0 = (tid & 3) * 16;

  for (int kb = 0; kb < 16; ++kb) {
    __syncthreads();
    {
      const float* kp = base + 768 + (long)(kb * 64 + kr) * 2304;
      const float* vp = base + 1536 + (long)(kb * 64 + kr) * 2304;
#pragma unroll
      for (int i = 0; i < 4; ++i) {
        int col = cc0 + i * 4;
        float4 kf = *(const float4*)(kp + col);
        ushort4 pk = make_ushort4(f2bf(kf.x), f2bf(kf.y), f2bf(kf.z), f2bf(kf.w));
        int kbyte = (kr * 128 + col * 2) ^ ((kr & 7) << 4);
        *(ushort4*)((char*)sK + kbyte) = pk;
        float4 vf = *(const float4*)(vp + col);
        u16 vv[4] = {f2bf(vf.x), f2bf(vf.y), f2bf(vf.z), f2bf(vf.w)};
#pragma unroll
        for (int j = 0; j < 4; ++j) {
          int d = col + j;
          int vbyte = (d * 128 + kr * 2) ^ ((d & 7) << 4);
          *(u16*)((char*)sV + vbyte) = vv[j];
        }
      }
    }
    __syncthreads();

    // S = Q K^T  (C: row=q, col=k_local)
    facc sc[4] = {};
#pragma unroll
    for (int f = 0; f < 4; ++f) {
      int row = f * 16 + c;
#pragma unroll
      for (int ss = 0; ss < 2; ++ss) {
        int byte = row * 128 + ((((ss * 32 + g * 8) * 2)) ^ ((row & 7) << 4));
        bfrag kf = *(const bfrag*)((const char*)sK + byte);
        sc[f] = __builtin_amdgcn_mfma_f32_16x16x32_bf16(qa[ss], kf, sc[f], 0, 0, 0);
      }
    }
#pragma unroll
    for (int f = 0; f < 4; ++f) sc[f] *= 0.125f;   // 1/sqrt(64)

    // online softmax; lane holds rows g*4+r, cols f*16+c
    u16 pb[4][4];
#pragma unroll
    for (int r = 0; r < 4; ++r) {
      float mx = fmaxf(fmaxf(sc[0][r], sc[1][r]), fmaxf(sc[2][r], sc[3][r]));
#pragma unroll
      for (int d = 1; d < 16; d <<= 1) mx = fmaxf(mx, __shfl_xor(mx, d));
      float mnew = fmaxf(m[r], mx);
      float alpha = __expf(m[r] - mnew);
      m[r] = mnew;
      float sum = 0.0f;
#pragma unroll
      for (int f = 0; f < 4; ++f) {
        float p = __expf(sc[f][r] - mnew);
        pb[f][r] = f2bf(p);
        sum += p;
      }
#pragma unroll
      for (int d = 1; d < 16; d <<= 1) sum += __shfl_xor(sum, d);
      l[r] = l[r] * alpha + sum;
      o[0][r] *= alpha; o[1][r] *= alpha; o[2][r] *= alpha; o[3][r] *= alpha;
    }

    // write P tile (bf16) to per-wave LDS
#pragma unroll
    for (int f = 0; f < 4; ++f)
#pragma unroll
      for (int r = 0; r < 4; ++r) {
        int row = g * 4 + r;
        int col = f * 16 + c;
        int byte = (row * 128 + col * 2) ^ ((row & 7) << 4);
        *(u16*)((char*)sP[wave] + byte) = pb[f][r];
      }
    __syncthreads();

    // O += P @ V   (A = P from LDS, B = V via V^T tile)
#pragma unroll
    for (int ss = 0; ss < 2; ++ss) {
      int pbyte = c * 128 + ((((ss * 32 + g * 8) * 2)) ^ ((c & 7) << 4));
      bfrag pa = *(const bfrag*)((const char*)sP[wave] + pbyte);
#pragma unroll
      for (int fo = 0; fo < 4; ++fo) {
        int drow = fo * 16 + c;
        int vbyte = drow * 128 + ((((ss * 32 + g * 8) * 2)) ^ ((drow & 7) << 4));
        bfrag vb = *(const bfrag*)((const char*)sV + vbyte);
        o[fo] = __builtin_amdgcn_mfma_f32_16x16x32_bf16(pa, vb, o[fo], 0, 0, 0);
      }
    }
  }

  // normalize and emit split bf16
#pragma unroll
  for (int r = 0; r < 4; ++r) {
    float inv = 1.0f / l[r];
    long row = (long)b * 1024 + qt * 64 + wave * 16 + g * 4 + r;
#pragma unroll
    for (int fo = 0; fo < 4; ++fo) {
      long col = hh * 64 + fo * 16 + c;
      float v = o[fo][r] * inv;
      u16 hi, lo;
      splitbf(v, hi, lo);
      ohi[row * 768 + col] = hi;
      olo[row * 768 + col] = lo;
    }
  }
}

// ---------- host ----------
extern "C" void kernel_launch(void* const* d_in, const int* in_sizes, int n_in,
                              void* d_out, int out_size, void* d_ws, size_t ws_size,
                              hipStream_t stream) {
  const int*   x     = (const int*)d_in[0];
  const float* tok   = (const float*)d_in[1];
  const float* pos   = (const float*)d_in[2];
  const float* ln1g  = (const float*)d_in[3];
  const float* ln1b  = (const float*)d_in[4];
  const float* Wqkv  = (const float*)d_in[5];
  const float* bqkv  = (const float*)d_in[6];
  const float* Wproj = (const float*)d_in[7];
  const float* bproj = (const float*)d_in[8];
  const float* ln2g  = (const float*)d_in[9];
  const float* ln2b  = (const float*)d_in[10];
  const float* Wff1  = (const float*)d_in[11];
  const float* bff1  = (const float*)d_in[12];
  const float* Wff2  = (const float*)d_in[13];
  const float* bff2  = (const float*)d_in[14];
  const float* lnfg  = (const float*)d_in[15];
  const float* lnfb  = (const float*)d_in[16];
  float* out = (float*)d_out;

  char* p = (char*)d_ws;
  auto alloc = [&](size_t bytes) {
    char* r = p;
    p += (bytes + 255) & ~(size_t)255;
    return r;
  };
  float* h   = (float*)alloc(8192ll * 768 * 4);
  u16* a_hi  = (u16*)alloc(8192ll * 768 * 2);
  u16* a_lo  = (u16*)alloc(8192ll * 768 * 2);
  float* qkv = (float*)alloc(8192ll * 2304 * 4);
  u16* o_hi  = (u16*)alloc(8192ll * 768 * 2);
  u16* o_lo  = (u16*)alloc(8192ll * 768 * 2);
  u16* f_hi  = (u16*)alloc(8192ll * 3072 * 2);
  u16* f_lo  = (u16*)alloc(8192ll * 3072 * 2);
  u16* w_hi  = (u16*)alloc(3072ll * 768 * 2);
  u16* w_lo  = (u16*)alloc(3072ll * 768 * 2);
  u16* t_hi  = (u16*)alloc(256ll * 768 * 2);
  u16* t_lo  = (u16*)alloc(256ll * 768 * 2);

  embed_kernel<<<6144, 256, 0, stream>>>(x, tok, pos, h);
  split_kernel<<<192, 256, 0, stream>>>(tok, t_hi, t_lo, 49152);

  for (int l = 0; l < 8; ++l) {
    ln_split_kernel<<<8192, 256, 0, stream>>>(h, ln1g + l * 768, ln1b + l * 768, a_hi, a_lo);
    tsplit_kernel<<<dim3(72, 24), 256, 0, stream>>>(Wqkv + (long)l * 768 * 2304, w_hi, w_lo, 768, 2304);
    gemm_bt<0><<<64 * 18, 256, 0, stream>>>(a_hi, a_lo, w_hi, w_lo, 8192, 2304, 768,
                                            bqkv + l * 2304, nullptr, qkv, nullptr, nullptr);
    attn_kernel<<<1536, 256, 0, stream>>>(qkv, o_hi, o_lo);
    tsplit_kernel<<<dim3(24, 24), 256, 0, stream>>>(Wproj + (long)l * 768 * 768, w_hi, w_lo, 768, 768);
    gemm_bt<1><<<64 * 6, 256, 0, stream>>>(o_hi, o_lo, w_hi, w_lo, 8192, 768, 768,
                                           bproj + l * 768, h, h, nullptr, nullptr);
    ln_split_kernel<<<8192, 256, 0, stream>>>(h, ln2g + l * 768, ln2b + l * 768, a_hi, a_lo);
    tsplit_kernel<<<dim3(96, 24), 256, 0, stream>>>(Wff1 + (long)l * 768 * 3072, w_hi, w_lo, 768, 3072);
    gemm_bt<2><<<64 * 24, 256, 0, stream>>>(a_hi, a_lo, w_hi, w_lo, 8192, 3072, 768,
                                            bff1 + l * 3072, nullptr, nullptr, f_hi, f_lo);
    tsplit_kernel<<<dim3(24, 96), 256, 0, stream>>>(Wff2 + (long)l * 3072 * 768, w_hi, w_lo, 3072, 768);
    gemm_bt<1><<<64 * 6, 256, 0, stream>>>(f_hi, f_lo, w_hi, w_lo, 8192, 768, 3072,
                                           bff2 + l * 768, h, h, nullptr, nullptr);
  }
  ln_split_kernel<<<8192, 256, 0, stream>>>(h, lnfg, lnfb, a_hi, a_lo);
  gemm_bt<3><<<64 * 2, 256, 0, stream>>>(a_hi, a_lo, t_hi, t_lo, 8192, 256, 768,
                                         nullptr, nullptr, out, nullptr, nullptr);
}

// Round 5
// 4442.898 us; speedup vs baseline: 1.1740x; 1.1740x over previous
//
#include <hip/hip_runtime.h>

typedef unsigned short u16;
typedef __attribute__((ext_vector_type(8))) short bfrag;   // 8 bf16 in 4 VGPRs
typedef __attribute__((ext_vector_type(8))) unsigned short us8;
typedef __attribute__((ext_vector_type(4))) float facc;    // MFMA accumulator

// ---------- fp32 -> bf16 split helpers ----------
__device__ __forceinline__ u16 f2bf(float x) {
  unsigned u = __float_as_uint(x);
  u += 0x7fffu + ((u >> 16) & 1u);     // round-to-nearest-even
  return (u16)(u >> 16);
}
__device__ __forceinline__ float bf2f(u16 h) {
  return __uint_as_float(((unsigned)h) << 16);
}
__device__ __forceinline__ void splitbf(float x, u16 &hi, u16 &lo) {
  u16 h = f2bf(x);
  hi = h;
  lo = f2bf(x - bf2f(h));
}

// ---------- async global->LDS, 16B per lane, wave-uniform LDS base ----------
__device__ __forceinline__ void gload16(const u16* g, u16* l) {
  __builtin_amdgcn_global_load_lds((const __attribute__((address_space(1))) void*)g,
                                   (__attribute__((address_space(3))) void*)l, 16, 0, 0);
}

// ---------- embedding: h = tok_emb[x] + pos_emb ----------
__global__ void embed_kernel(const int* __restrict__ x, const float* __restrict__ tok,
                             const float* __restrict__ pos, float* __restrict__ h) {
  int i = blockIdx.x * 256 + threadIdx.x;      // over 8192*192 float4
  int m = i / 192;
  int d4 = i % 192;
  int v = x[m];
  float4 t = ((const float4*)tok)[(long)v * 192 + d4];
  float4 p = ((const float4*)pos)[(long)(m & 1023) * 192 + d4];
  float4 r;
  r.x = t.x + p.x; r.y = t.y + p.y; r.z = t.z + p.z; r.w = t.w + p.w;
  ((float4*)h)[i] = r;
}

// ---------- plain split convert (no transpose), float4-granular ----------
__global__ void split_kernel(const float* __restrict__ in, u16* __restrict__ ohi,
                             u16* __restrict__ olo, int n4) {
  int i = blockIdx.x * 256 + threadIdx.x;
  if (i >= n4) return;
  float4 v = ((const float4*)in)[i];
  ushort4 h4, l4;
  splitbf(v.x, h4.x, l4.x);
  splitbf(v.y, h4.y, l4.y);
  splitbf(v.z, h4.z, l4.z);
  splitbf(v.w, h4.w, l4.w);
  ((ushort4*)ohi)[i] = h4;
  ((ushort4*)olo)[i] = l4;
}

// ---------- transpose + split: W[K][N] fp32 -> WT_hi/lo [N][K] bf16 ----------
__global__ __launch_bounds__(256)
void tsplit_kernel(const float* __restrict__ W, u16* __restrict__ ohi,
                   u16* __restrict__ olo, int K, int N) {
  __shared__ float tile[32][33];
  const int tx = threadIdx.x & 31, ty = threadIdx.x >> 5;
  const long n0 = (long)blockIdx.x * 32, k0 = (long)blockIdx.y * 32;
#pragma unroll
  for (int r = 0; r < 4; ++r) {
    int kk = ty + r * 8;
    tile[kk][tx] = W[(k0 + kk) * N + n0 + tx];
  }
  __syncthreads();
#pragma unroll
  for (int r = 0; r < 4; ++r) {
    int nn = ty + r * 8;
    float v = tile[tx][nn];
    u16 hi, lo;
    splitbf(v, hi, lo);
    long off = (n0 + nn) * K + k0 + tx;
    ohi[off] = hi;
    olo[off] = lo;
  }
}

// ---------- LayerNorm (D=768) + split output ----------
__global__ __launch_bounds__(256)
void ln_split_kernel(const float* __restrict__ x, const float* __restrict__ gam,
                     const float* __restrict__ bet, u16* __restrict__ ohi,
                     u16* __restrict__ olo) {
  const int row = blockIdx.x, tid = threadIdx.x;
  const float* xp = x + (long)row * 768;
  float v0 = xp[tid], v1 = xp[tid + 256], v2 = xp[tid + 512];
  float s = v0 + v1 + v2;
  float q = v0 * v0 + v1 * v1 + v2 * v2;
#pragma unroll
  for (int d = 32; d > 0; d >>= 1) {
    s += __shfl_xor(s, d);
    q += __shfl_xor(q, d);
  }
  __shared__ float red[8];
  const int wave = tid >> 6, lane = tid & 63;
  if (lane == 0) { red[wave] = s; red[4 + wave] = q; }
  __syncthreads();
  s = red[0] + red[1] + red[2] + red[3];
  q = red[4] + red[5] + red[6] + red[7];
  const float mu = s * (1.0f / 768.0f);
  const float var = q * (1.0f / 768.0f) - mu * mu;
  const float rstd = rsqrtf(var + 1e-5f);
  const long base = (long)row * 768;
  u16 hi, lo;
  float y0 = (v0 - mu) * rstd * gam[tid] + bet[tid];
  splitbf(y0, hi, lo); ohi[base + tid] = hi; olo[base + tid] = lo;
  float y1 = (v1 - mu) * rstd * gam[tid + 256] + bet[tid + 256];
  splitbf(y1, hi, lo); ohi[base + tid + 256] = hi; olo[base + tid + 256] = lo;
  float y2 = (v2 - mu) * rstd * gam[tid + 512] + bet[tid + 512];
  splitbf(y2, hi, lo); ohi[base + tid + 512] = hi; olo[base + tid + 512] = lo;
}

// ---------- split-bf16 GEMM, B^T layout: C[M][N] = A[M][K] @ B(BT[N][K]) ----------
// 128x128 tile, BK=64, 4 waves (2x2 of 64x64), 3-term split MFMA.
// Staging: global_load_lds width=16, linear LDS dest + pre-swizzled global source
// (slot ^= row&7) so the read-side XOR layout is unchanged.
// EPI: 0 = +bias -> f32 ; 1 = +bias+res -> f32 ; 2 = +bias, GELU -> split bf16 ;
//      3 = plain -> f32 ; 4 = +bias -> bf16 scattered to Q/K/V [B,H,T,64]
template <int EPI>
__global__ __launch_bounds__(256, 2)
void gemm_bt(const u16* __restrict__ Ahi, const u16* __restrict__ Alo,
             const u16* __restrict__ Bhi, const u16* __restrict__ Blo,
             int M, int N, int K, const float* __restrict__ bias,
             const float* res, float* outf, u16* outhi, u16* outlo, u16* outv) {
  __shared__ u16 lds[4 * 128 * 64];          // 64 KB: Ahi, Alo, Bhi, Blo tiles
  u16* sAh = lds;
  u16* sAl = lds + 8192;
  u16* sBh = lds + 16384;
  u16* sBl = lds + 24576;

  const int tid = threadIdx.x;
  const int lane = tid & 63, wave = tid >> 6;
  const int g = lane >> 4, c = lane & 15;
  const int nb = N >> 7;
  const int mt = blockIdx.x / nb, nt = blockIdx.x % nb;
  const long m0 = (long)mt << 7, n0 = (long)nt << 7;
  const int wm = (wave >> 1) << 6, wn = (wave & 1) << 6;

  facc acc[4][4] = {};

  int arow[4], brow[4];
#pragma unroll
  for (int i = 0; i < 4; ++i) {
    arow[i] = wm + i * 16 + c;
    brow[i] = wn + i * 16 + c;
  }

  const int nkt = K >> 6;
  for (int kt = 0; kt < nkt; ++kt) {
    __syncthreads();                          // prev-iter reads drained before DMA overwrite
    {
      const long kcol = (long)kt * 64;
#pragma unroll
      for (int i = 0; i < 4; ++i) {
        const int ci = (wave * 4 + i) * 64 + lane;       // chunk 0..1023
        const int row = ci >> 3;
        const int slot = (ci & 7) ^ (row & 7);           // pre-swizzled source slot
        const long ga = (m0 + row) * (long)K + kcol + slot * 8;
        const long gb = (n0 + row) * (long)K + kcol + slot * 8;
        const int lb = (wave * 4 + i) * 512;             // wave-uniform LDS base (u16)
        gload16(Ahi + ga, sAh + lb);
        gload16(Alo + ga, sAl + lb);
        gload16(Bhi + gb, sBh + lb);
        gload16(Blo + gb, sBl + lb);
      }
    }
    __syncthreads();                          // compiler drains vmcnt(0) before barrier
#pragma unroll
    for (int ks = 0; ks < 2; ++ks) {
      const int kb = (ks * 32 + g * 8) * 2;              // byte offset of this lane's k-slice
      bfrag ah[4], al[4], bh[4], bl[4];
#pragma unroll
      for (int i = 0; i < 4; ++i) {
        int ab = arow[i] * 128 + (kb ^ ((arow[i] & 7) << 4));
        ah[i] = *(const bfrag*)((const char*)sAh + ab);
        al[i] = *(const bfrag*)((const char*)sAl + ab);
        int bb = brow[i] * 128 + (kb ^ ((brow[i] & 7) << 4));
        bh[i] = *(const bfrag*)((const char*)sBh + bb);
        bl[i] = *(const bfrag*)((const char*)sBl + bb);
      }
#pragma unroll
      for (int mi = 0; mi < 4; ++mi)
#pragma unroll
        for (int ni = 0; ni < 4; ++ni) {
          acc[mi][ni] = __builtin_amdgcn_mfma_f32_16x16x32_bf16(ah[mi], bh[ni], acc[mi][ni], 0, 0, 0);
          acc[mi][ni] = __builtin_amdgcn_mfma_f32_16x16x32_bf16(ah[mi], bl[ni], acc[mi][ni], 0, 0, 0);
          acc[mi][ni] = __builtin_amdgcn_mfma_f32_16x16x32_bf16(al[mi], bh[ni], acc[mi][ni], 0, 0, 0);
        }
    }
  }

#pragma unroll
  for (int mi = 0; mi < 4; ++mi)
#pragma unroll
    for (int ni = 0; ni < 4; ++ni)
#pragma unroll
      for (int r = 0; r < 4; ++r) {
        long row = m0 + wm + mi * 16 + g * 4 + r;        // C/D: col=lane&15, row=(lane>>4)*4+reg
        long col = n0 + wn + ni * 16 + c;
        float v = acc[mi][ni][r];
        if (EPI != 3) v += bias[col];
        if (EPI == 1) v += res[row * N + col];
        if (EPI == 2) {
          v = 0.5f * v * (1.0f + erff(v * 0.70710678118654752f));
          u16 hi, lo;
          splitbf(v, hi, lo);
          outhi[row * N + col] = hi;
          outlo[row * N + col] = lo;
        } else if (EPI == 4) {
          int sc_ = (int)col;
          u16* dst;
          if (sc_ >= 1536) { dst = outv; sc_ -= 1536; }
          else if (sc_ >= 768) { dst = outlo; sc_ -= 768; }
          else dst = outhi;
          int hh = sc_ >> 6, dd = sc_ & 63;
          long addr = ((((row >> 10) * 12 + hh) << 10) + (row & 1023)) * 64 + dd;
          dst[addr] = f2bf(v);
        } else {
          outf[row * N + col] = v;
        }
      }
}

// ---------- fused flash attention v2: bf16 in [B,H,T,64], 128-row q-tiles ----------
// grid: 96 bh * 8 qtiles = 768 blocks, 256 threads (4 waves); wave owns 32 q rows.
// K/V double-buffered in LDS (swizzled), issue-early/write-late staging, 1 barrier/iter.
__global__ __launch_bounds__(256, 2)
void attn_kernel(const u16* __restrict__ Qb, const u16* __restrict__ Kb,
                 const u16* __restrict__ Vb, u16* __restrict__ ohi,
                 u16* __restrict__ olo) {
  __shared__ u16 sK[2][4096];        // [k][d] swizzled, double-buffered
  __shared__ u16 sV[2][4096];        // V^T [d][k] swizzled, double-buffered
  __shared__ u16 sP[4][2048];        // per-wave P tile [32 q][64 k] swizzled
  const int tid = threadIdx.x;
  const int lane = tid & 63, w = tid >> 6;
  const int g = lane >> 4, c = lane & 15;
  const int qt = blockIdx.x & 7, bh = blockIdx.x >> 3;
  const int b = bh / 12, hh = bh % 12;
  const long kvbase = (long)bh * 1024 * 64;

  // Q fragments in registers, pre-scaled by 1/sqrt(64)=0.125 (exact pow2 in bf16)
  bfrag qa[2][2];
#pragma unroll
  for (int mi = 0; mi < 2; ++mi)
#pragma unroll
    for (int ss = 0; ss < 2; ++ss) {
      int qr = qt * 128 + w * 32 + mi * 16 + c;
      us8 t = *(const us8*)(Qb + kvbase + (long)qr * 64 + ss * 32 + g * 8);
      bfrag q_;
#pragma unroll
      for (int j = 0; j < 8; ++j) q_[j] = (short)f2bf(bf2f(t[j]) * 0.125f);
      qa[mi][ss] = q_;
    }

  facc o[2][4] = {};
  float m_[2][4], l_[2][4];
#pragma unroll
  for (int mi = 0; mi < 2; ++mi)
#pragma unroll
    for (int r = 0; r < 4; ++r) { m_[mi][r] = -1e30f; l_[mi][r] = 0.0f; }

  // staging: 512 chunks of 16B (K) + 512 (V), 2 per thread each
  const int kr0 = tid >> 3, sl0 = (tid & 7);
  const int kr1 = (tid + 256) >> 3, sl1 = (tid & 7);
  us8 kreg[2], vreg[2];

  auto stage_load = [&](int kb) {
    const u16* kp = Kb + kvbase + (long)kb * 64 * 64;
    const u16* vp = Vb + kvbase + (long)kb * 64 * 64;
    kreg[0] = *(const us8*)(kp + kr0 * 64 + sl0 * 8);
    kreg[1] = *(const us8*)(kp + kr1 * 64 + sl1 * 8);
    vreg[0] = *(const us8*)(vp + kr0 * 64 + sl0 * 8);
    vreg[1] = *(const us8*)(vp + kr1 * 64 + sl1 * 8);
  };
  auto stage_write = [&](int buf) {
    *(us8*)((char*)sK[buf] + ((kr0 * 128 + sl0 * 16) ^ ((kr0 & 7) << 4))) = kreg[0];
    *(us8*)((char*)sK[buf] + ((kr1 * 128 + sl1 * 16) ^ ((kr1 & 7) << 4))) = kreg[1];
#pragma unroll
    for (int j = 0; j < 8; ++j) {
      int d0 = sl0 * 8 + j;
      *(u16*)((char*)sV[buf] + ((d0 * 128 + kr0 * 2) ^ ((d0 & 7) << 4))) = vreg[0][j];
      int d1 = sl1 * 8 + j;
      *(u16*)((char*)sV[buf] + ((d1 * 128 + kr1 * 2) ^ ((d1 & 7) << 4))) = vreg[1][j];
    }
  };

  stage_load(0);
  stage_write(0);
  __syncthreads();

  for (int kb = 0; kb < 16; ++kb) {
    const int cur = kb & 1;
    if (kb < 15) stage_load(kb + 1);           // issue early; consumed at stage_write

    // S = Q K^T : C row = q (within wave's 32), col = key
    facc sc[2][4] = {};
#pragma unroll
    for (int ss = 0; ss < 2; ++ss) {
      const int kcol2 = (ss * 32 + g * 8) * 2;
#pragma unroll
      for (int f = 0; f < 4; ++f) {
        int krow = f * 16 + c;
        bfrag kf = *(const bfrag*)((const char*)sK[cur] +
                                   ((krow * 128 + kcol2) ^ ((krow & 7) << 4)));
        sc[0][f] = __builtin_amdgcn_mfma_f32_16x16x32_bf16(qa[0][ss], kf, sc[0][f], 0, 0, 0);
        sc[1][f] = __builtin_amdgcn_mfma_f32_16x16x32_bf16(qa[1][ss], kf, sc[1][f], 0, 0, 0);
      }
    }

    // online softmax; lane holds rows mi*16+g*4+r, cols f*16+c
#pragma unroll
    for (int mi = 0; mi < 2; ++mi)
#pragma unroll
      for (int r = 0; r < 4; ++r) {
        float mx = fmaxf(fmaxf(sc[mi][0][r], sc[mi][1][r]), fmaxf(sc[mi][2][r], sc[mi][3][r]));
#pragma unroll
        for (int d = 1; d < 16; d <<= 1) mx = fmaxf(mx, __shfl_xor(mx, d));
        float mn = fmaxf(m_[mi][r], mx);
        float al = __expf(m_[mi][r] - mn);
        m_[mi][r] = mn;
        float sum = 0.0f;
        u16 pb[4];
#pragma unroll
        for (int f = 0; f < 4; ++f) {
          float p = __expf(sc[mi][f][r] - mn);
          pb[f] = f2bf(p);
          sum += p;
        }
#pragma unroll
        for (int d = 1; d < 16; d <<= 1) sum += __shfl_xor(sum, d);
        l_[mi][r] = l_[mi][r] * al + sum;
#pragma unroll
        for (int fo = 0; fo < 4; ++fo) o[mi][fo][r] *= al;
        int prow = mi * 16 + g * 4 + r;
#pragma unroll
        for (int f = 0; f < 4; ++f) {
          int byte_ = (prow * 128 + (f * 16 + c) * 2) ^ ((prow & 7) << 4);
          *(u16*)((char*)sP[w] + byte_) = pb[f];
        }
      }

    // O += P @ V  (P per-wave in LDS; wave-ordered LDS ops, no block barrier)
#pragma unroll
    for (int ss = 0; ss < 2; ++ss) {
      const int kcol2 = (ss * 32 + g * 8) * 2;
      bfrag pa[2], vb[4];
#pragma unroll
      for (int mi = 0; mi < 2; ++mi) {
        int prow = mi * 16 + c;
        pa[mi] = *(const bfrag*)((const char*)sP[w] +
                                 ((prow * 128 + kcol2) ^ ((prow & 7) << 4)));
      }
#pragma unroll
      for (int fo = 0; fo < 4; ++fo) {
        int drow = fo * 16 + c;
        vb[fo] = *(const bfrag*)((const char*)sV[cur] +
                                 ((drow * 128 + kcol2) ^ ((drow & 7) << 4)));
      }
#pragma unroll
      for (int mi = 0; mi < 2; ++mi)
#pragma unroll
        for (int fo = 0; fo < 4; ++fo)
          o[mi][fo] = __builtin_amdgcn_mfma_f32_16x16x32_bf16(pa[mi], vb[fo], o[mi][fo], 0, 0, 0);
    }

    if (kb < 15) {
      stage_write(cur ^ 1);    // waits vmcnt for kreg/vreg here (compiler-inserted)
      __syncthreads();
    }
  }

  // normalize and emit split bf16
#pragma unroll
  for (int mi = 0; mi < 2; ++mi)
#pragma unroll
    for (int r = 0; r < 4; ++r) {
      float inv = 1.0f / l_[mi][r];
      long row = (long)b * 1024 + qt * 128 + w * 32 + mi * 16 + g * 4 + r;
#pragma unroll
      for (int fo = 0; fo < 4; ++fo) {
        long col = hh * 64 + fo * 16 + c;
        float v = o[mi][fo][r] * inv;
        u16 hi, lo;
        splitbf(v, hi, lo);
        ohi[row * 768 + col] = hi;
        olo[row * 768 + col] = lo;
      }
    }
}

// ---------- host ----------
extern "C" void kernel_launch(void* const* d_in, const int* in_sizes, int n_in,
                              void* d_out, int out_size, void* d_ws, size_t ws_size,
                              hipStream_t stream) {
  const int*   x     = (const int*)d_in[0];
  const float* tok   = (const float*)d_in[1];
  const float* pos   = (const float*)d_in[2];
  const float* ln1g  = (const float*)d_in[3];
  const float* ln1b  = (const float*)d_in[4];
  const float* Wqkv  = (const float*)d_in[5];
  const float* bqkv  = (const float*)d_in[6];
  const float* Wproj = (const float*)d_in[7];
  const float* bproj = (const float*)d_in[8];
  const float* ln2g  = (const float*)d_in[9];
  const float* ln2b  = (const float*)d_in[10];
  const float* Wff1  = (const float*)d_in[11];
  const float* bff1  = (const float*)d_in[12];
  const float* Wff2  = (const float*)d_in[13];
  const float* bff2  = (const float*)d_in[14];
  const float* lnfg  = (const float*)d_in[15];
  const float* lnfb  = (const float*)d_in[16];
  float* out = (float*)d_out;

  char* p = (char*)d_ws;
  auto alloc = [&](size_t bytes) {
    char* r = p;
    p += (bytes + 255) & ~(size_t)255;
    return r;
  };
  float* h   = (float*)alloc(8192ll * 768 * 4);
  u16* a_hi  = (u16*)alloc(8192ll * 768 * 2);
  u16* a_lo  = (u16*)alloc(8192ll * 768 * 2);
  u16* Qb    = (u16*)alloc(8192ll * 768 * 2);   // [B,H,T,64] bf16
  u16* Kbuf  = (u16*)alloc(8192ll * 768 * 2);
  u16* Vbuf  = (u16*)alloc(8192ll * 768 * 2);
  u16* o_hi  = (u16*)alloc(8192ll * 768 * 2);
  u16* o_lo  = (u16*)alloc(8192ll * 768 * 2);
  u16* f_hi  = (u16*)alloc(8192ll * 3072 * 2);
  u16* f_lo  = (u16*)alloc(8192ll * 3072 * 2);
  u16* w_hi  = (u16*)alloc(3072ll * 768 * 2);
  u16* w_lo  = (u16*)alloc(3072ll * 768 * 2);
  u16* t_hi  = (u16*)alloc(256ll * 768 * 2);
  u16* t_lo  = (u16*)alloc(256ll * 768 * 2);

  embed_kernel<<<6144, 256, 0, stream>>>(x, tok, pos, h);
  split_kernel<<<192, 256, 0, stream>>>(tok, t_hi, t_lo, 49152);

  for (int l = 0; l < 8; ++l) {
    ln_split_kernel<<<8192, 256, 0, stream>>>(h, ln1g + l * 768, ln1b + l * 768, a_hi, a_lo);
    tsplit_kernel<<<dim3(72, 24), 256, 0, stream>>>(Wqkv + (long)l * 768 * 2304, w_hi, w_lo, 768, 2304);
    gemm_bt<4><<<64 * 18, 256, 0, stream>>>(a_hi, a_lo, w_hi, w_lo, 8192, 2304, 768,
                                            bqkv + l * 2304, nullptr, nullptr, Qb, Kbuf, Vbuf);
    attn_kernel<<<768, 256, 0, stream>>>(Qb, Kbuf, Vbuf, o_hi, o_lo);
    tsplit_kernel<<<dim3(24, 24), 256, 0, stream>>>(Wproj + (long)l * 768 * 768, w_hi, w_lo, 768, 768);
    gemm_bt<1><<<64 * 6, 256, 0, stream>>>(o_hi, o_lo, w_hi, w_lo, 8192, 768, 768,
                                           bproj + l * 768, h, h, nullptr, nullptr, nullptr);
    ln_split_kernel<<<8192, 256, 0, stream>>>(h, ln2g + l * 768, ln2b + l * 768, a_hi, a_lo);
    tsplit_kernel<<<dim3(96, 24), 256, 0, stream>>>(Wff1 + (long)l * 768 * 3072, w_hi, w_lo, 768, 3072);
    gemm_bt<2><<<64 * 24, 256, 0, stream>>>(a_hi, a_lo, w_hi, w_lo, 8192, 3072, 768,
                                            bff1 + l * 3072, nullptr, nullptr, f_hi, f_lo, nullptr);
    tsplit_kernel<<<dim3(24, 96), 256, 0, stream>>>(Wff2 + (long)l * 3072 * 768, w_hi, w_lo, 3072, 768);
    gemm_bt<1><<<64 * 6, 256, 0, stream>>>(f_hi, f_lo, w_hi, w_lo, 8192, 768, 3072,
                                           bff2 + l * 768, h, h, nullptr, nullptr, nullptr);
  }
  ln_split_kernel<<<8192, 256, 0, stream>>>(h, lnfg, lnfb, a_hi, a_lo);
  gemm_bt<3><<<64 * 2, 256, 0, stream>>>(a_hi, a_lo, t_hi, t_lo, 8192, 256, 768,
                                         nullptr, nullptr, out, nullptr, nullptr, nullptr);
}

// Round 6
// 2928.660 us; speedup vs baseline: 1.7811x; 1.5170x over previous
//
#include <hip/hip_runtime.h>

typedef unsigned short u16;
typedef _Float16 f16;
typedef __attribute__((ext_vector_type(8))) _Float16 hfrag;  // 8 fp16 in 4 VGPRs
typedef __attribute__((ext_vector_type(4))) _Float16 h4;
typedef __attribute__((ext_vector_type(8))) short bfrag;     // 8 bf16
typedef __attribute__((ext_vector_type(8))) unsigned short us8;
typedef __attribute__((ext_vector_type(4))) float facc;

// ---------- bf16 helpers (attention path) ----------
__device__ __forceinline__ u16 f2bf(float x) {
  unsigned u = __float_as_uint(x);
  u += 0x7fffu + ((u >> 16) & 1u);
  return (u16)(u >> 16);
}
__device__ __forceinline__ float bf2f(u16 h) {
  return __uint_as_float(((unsigned)h) << 16);
}

// ---------- async global->LDS, 16B per lane ----------
__device__ __forceinline__ void gload16(const void* g, void* l) {
  __builtin_amdgcn_global_load_lds((const __attribute__((address_space(1))) void*)g,
                                   (__attribute__((address_space(3))) void*)l, 16, 0, 0);
}

// ---------- embedding: h = tok_emb[x] + pos_emb ----------
__global__ void embed_kernel(const int* __restrict__ x, const float* __restrict__ tok,
                             const float* __restrict__ pos, float* __restrict__ h) {
  int i = blockIdx.x * 256 + threadIdx.x;      // over 8192*192 float4
  int m = i / 192;
  int d4 = i % 192;
  int v = x[m];
  float4 t = ((const float4*)tok)[(long)v * 192 + d4];
  float4 p = ((const float4*)pos)[(long)(m & 1023) * 192 + d4];
  float4 r;
  r.x = t.x + p.x; r.y = t.y + p.y; r.z = t.z + p.z; r.w = t.w + p.w;
  ((float4*)h)[i] = r;
}

// ---------- elementwise fp32 -> fp16 (x64 scale), for tied head tok_emb ----------
__global__ void half_kernel(const float* __restrict__ in, f16* __restrict__ oh, int n4) {
  int i = blockIdx.x * 256 + threadIdx.x;
  if (i >= n4) return;
  float4 v = ((const float4*)in)[i];
  h4 r;
  r[0] = (f16)(v.x * 64.0f); r[1] = (f16)(v.y * 64.0f);
  r[2] = (f16)(v.z * 64.0f); r[3] = (f16)(v.w * 64.0f);
  ((h4*)oh)[i] = r;
}

// ---------- transpose + fp16 (x64): W[K][N] fp32 -> WT[N][K] fp16 ----------
__global__ __launch_bounds__(256)
void thalf_kernel(const float* __restrict__ W, f16* __restrict__ oh, int K, int N) {
  __shared__ float tile[32][33];
  const int tx = threadIdx.x & 31, ty = threadIdx.x >> 5;
  const long n0 = (long)blockIdx.x * 32, k0 = (long)blockIdx.y * 32;
#pragma unroll
  for (int r = 0; r < 4; ++r) {
    int kk = ty + r * 8;
    tile[kk][tx] = W[(k0 + kk) * N + n0 + tx];
  }
  __syncthreads();
#pragma unroll
  for (int r = 0; r < 4; ++r) {
    int nn = ty + r * 8;
    oh[(n0 + nn) * K + k0 + tx] = (f16)(tile[tx][nn] * 64.0f);
  }
}

// ---------- LayerNorm (D=768) -> fp16 ----------
__global__ __launch_bounds__(256)
void ln_half_kernel(const float* __restrict__ x, const float* __restrict__ gam,
                    const float* __restrict__ bet, f16* __restrict__ oh) {
  const int row = blockIdx.x, tid = threadIdx.x;
  const float* xp = x + (long)row * 768;
  float v0 = xp[tid], v1 = xp[tid + 256], v2 = xp[tid + 512];
  float s = v0 + v1 + v2;
  float q = v0 * v0 + v1 * v1 + v2 * v2;
#pragma unroll
  for (int d = 32; d > 0; d >>= 1) {
    s += __shfl_xor(s, d);
    q += __shfl_xor(q, d);
  }
  __shared__ float red[8];
  const int wave = tid >> 6, lane = tid & 63;
  if (lane == 0) { red[wave] = s; red[4 + wave] = q; }
  __syncthreads();
  s = red[0] + red[1] + red[2] + red[3];
  q = red[4] + red[5] + red[6] + red[7];
  const float mu = s * (1.0f / 768.0f);
  const float var = q * (1.0f / 768.0f) - mu * mu;
  const float rstd = rsqrtf(var + 1e-5f);
  const long base = (long)row * 768;
  oh[base + tid]       = (f16)((v0 - mu) * rstd * gam[tid] + bet[tid]);
  oh[base + tid + 256] = (f16)((v1 - mu) * rstd * gam[tid + 256] + bet[tid + 256]);
  oh[base + tid + 512] = (f16)((v2 - mu) * rstd * gam[tid + 512] + bet[tid + 512]);
}

// ---------- plain fp16 GEMM, B^T layout: C[M][N] = (A[M][K] @ BT[N][K]) / 64 ----------
// 128x128 tile, BK=64, 4 waves. global_load_lds staging, pre-swizzled source.
// B carries x64 weight scale -> epilogue x(1/64).
// EPI: 1 = +bias+res -> f32 ; 2 = +bias, GELU -> fp16 ; 3 = plain -> f32 ;
//      4 = +bias -> bf16 scattered to Q/K/V [B,H,T,64]
template <int EPI>
__global__ __launch_bounds__(256, 3)
void gemm_f16(const f16* __restrict__ A, const f16* __restrict__ B,
              int M, int N, int K, const float* __restrict__ bias,
              const float* res, float* outf, f16* outh,
              u16* outq, u16* outk, u16* outv) {
  __shared__ f16 lds[2 * 128 * 64];          // 32 KB: A tile, B tile
  f16* sA = lds;
  f16* sB = lds + 8192;

  const int tid = threadIdx.x;
  const int lane = tid & 63, wave = tid >> 6;
  const int g = lane >> 4, c = lane & 15;
  const int nb = N >> 7;
  const int nwg = gridDim.x;
  const int swz = (blockIdx.x & 7) * (nwg >> 3) + (blockIdx.x >> 3);  // XCD swizzle (nwg%8==0)
  const int mt = swz / nb, nt = swz % nb;
  const long m0 = (long)mt << 7, n0 = (long)nt << 7;
  const int wm = (wave >> 1) << 6, wn = (wave & 1) << 6;

  facc acc[4][4] = {};

  int arow[4], brow[4];
#pragma unroll
  for (int i = 0; i < 4; ++i) {
    arow[i] = wm + i * 16 + c;
    brow[i] = wn + i * 16 + c;
  }

  const int nkt = K >> 6;
  for (int kt = 0; kt < nkt; ++kt) {
    __syncthreads();                          // prev-iter reads drained before DMA overwrite
    {
      const long kcol = (long)kt * 64;
#pragma unroll
      for (int i = 0; i < 4; ++i) {
        const int ci = (wave * 4 + i) * 64 + lane;       // chunk 0..1023
        const int row = ci >> 3;
        const int slot = (ci & 7) ^ (row & 7);           // pre-swizzled source slot
        const long ga = (m0 + row) * (long)K + kcol + slot * 8;
        const long gb = (n0 + row) * (long)K + kcol + slot * 8;
        const int lb = (wave * 4 + i) * 512;             // wave-uniform LDS base (f16)
        gload16(A + ga, sA + lb);
        gload16(B + gb, sB + lb);
      }
    }
    __syncthreads();                          // vmcnt(0) drain before barrier
#pragma unroll
    for (int ks = 0; ks < 2; ++ks) {
      const int kb = (ks * 32 + g * 8) * 2;              // byte offset of this lane's k-slice
      hfrag ah[4], bh[4];
#pragma unroll
      for (int i = 0; i < 4; ++i) {
        int ab = arow[i] * 128 + (kb ^ ((arow[i] & 7) << 4));
        ah[i] = *(const hfrag*)((const char*)sA + ab);
        int bb = brow[i] * 128 + (kb ^ ((brow[i] & 7) << 4));
        bh[i] = *(const hfrag*)((const char*)sB + bb);
      }
#pragma unroll
      for (int mi = 0; mi < 4; ++mi)
#pragma unroll
        for (int ni = 0; ni < 4; ++ni)
          acc[mi][ni] = __builtin_amdgcn_mfma_f32_16x16x32_f16(ah[mi], bh[ni], acc[mi][ni], 0, 0, 0);
    }
  }

#pragma unroll
  for (int mi = 0; mi < 4; ++mi)
#pragma unroll
    for (int ni = 0; ni < 4; ++ni)
#pragma unroll
      for (int r = 0; r < 4; ++r) {
        long row = m0 + wm + mi * 16 + g * 4 + r;        // C/D: col=lane&15, row=(lane>>4)*4+reg
        long col = n0 + wn + ni * 16 + c;
        float v = acc[mi][ni][r] * 0.015625f;            // undo x64 weight scale
        if (EPI == 1) {
          outf[row * N + col] = v + bias[col] + res[row * N + col];
        } else if (EPI == 2) {
          v += bias[col];
          v = 0.5f * v * (1.0f + erff(v * 0.70710678118654752f));
          outh[row * N + col] = (f16)v;
        } else if (EPI == 4) {
          v += bias[col];
          int sc_ = (int)col;
          u16* dst;
          if (sc_ >= 1536) { dst = outv; sc_ -= 1536; }
          else if (sc_ >= 768) { dst = outk; sc_ -= 768; }
          else dst = outq;
          int hh = sc_ >> 6, dd = sc_ & 63;
          long addr = ((((row >> 10) * 12 + hh) << 10) + (row & 1023)) * 64 + dd;
          dst[addr] = f2bf(v);
        } else {                                          // EPI == 3 (head, no bias)
          outf[row * N + col] = v;
        }
      }
}

// ---------- fused flash attention: bf16 [B,H,T,64], 128-row q-tiles ----------
// grid 768 (XCD-swizzled so blocks sharing a KV head co-reside per XCD L2).
__global__ __launch_bounds__(256, 2)
void attn_kernel(const u16* __restrict__ Qb, const u16* __restrict__ Kb,
                 const u16* __restrict__ Vb, f16* __restrict__ oh) {
  __shared__ u16 sK[2][4096];        // [k][d] swizzled, double-buffered
  __shared__ u16 sV[2][4096];        // V^T [d][k] swizzled, double-buffered
  __shared__ u16 sP[4][2048];        // per-wave P tile [32 q][64 k] swizzled
  const int tid = threadIdx.x;
  const int lane = tid & 63, w = tid >> 6;
  const int g = lane >> 4, c = lane & 15;
  const int swz = (blockIdx.x & 7) * 96 + (blockIdx.x >> 3);
  const int qt = swz & 7, bh = swz >> 3;
  const int b = bh / 12, hh = bh % 12;
  const long kvbase = (long)bh * 1024 * 64;

  // Q fragments in registers, pre-scaled by 1/sqrt(64)=0.125 (exact pow2 in bf16)
  bfrag qa[2][2];
#pragma unroll
  for (int mi = 0; mi < 2; ++mi)
#pragma unroll
    for (int ss = 0; ss < 2; ++ss) {
      int qr = qt * 128 + w * 32 + mi * 16 + c;
      us8 t = *(const us8*)(Qb + kvbase + (long)qr * 64 + ss * 32 + g * 8);
      bfrag q_;
#pragma unroll
      for (int j = 0; j < 8; ++j) q_[j] = (short)f2bf(bf2f(t[j]) * 0.125f);
      qa[mi][ss] = q_;
    }

  facc o[2][4] = {};
  float m_[2][4], l_[2][4];
#pragma unroll
  for (int mi = 0; mi < 2; ++mi)
#pragma unroll
    for (int r = 0; r < 4; ++r) { m_[mi][r] = -1e30f; l_[mi][r] = 0.0f; }

  const int kr0 = tid >> 3, sl0 = (tid & 7);
  const int kr1 = (tid + 256) >> 3, sl1 = (tid & 7);
  us8 kreg[2], vreg[2];

  auto stage_load = [&](int kb) {
    const u16* kp = Kb + kvbase + (long)kb * 64 * 64;
    const u16* vp = Vb + kvbase + (long)kb * 64 * 64;
    kreg[0] = *(const us8*)(kp + kr0 * 64 + sl0 * 8);
    kreg[1] = *(const us8*)(kp + kr1 * 64 + sl1 * 8);
    vreg[0] = *(const us8*)(vp + kr0 * 64 + sl0 * 8);
    vreg[1] = *(const us8*)(vp + kr1 * 64 + sl1 * 8);
  };
  auto stage_write = [&](int buf) {
    *(us8*)((char*)sK[buf] + ((kr0 * 128 + sl0 * 16) ^ ((kr0 & 7) << 4))) = kreg[0];
    *(us8*)((char*)sK[buf] + ((kr1 * 128 + sl1 * 16) ^ ((kr1 & 7) << 4))) = kreg[1];
#pragma unroll
    for (int j = 0; j < 8; ++j) {
      int d0 = sl0 * 8 + j;
      *(u16*)((char*)sV[buf] + ((d0 * 128 + kr0 * 2) ^ ((d0 & 7) << 4))) = vreg[0][j];
      int d1 = sl1 * 8 + j;
      *(u16*)((char*)sV[buf] + ((d1 * 128 + kr1 * 2) ^ ((d1 & 7) << 4))) = vreg[1][j];
    }
  };

  stage_load(0);
  stage_write(0);
  __syncthreads();

  for (int kb = 0; kb < 16; ++kb) {
    const int cur = kb & 1;
    if (kb < 15) stage_load(kb + 1);           // issue early; consumed at stage_write

    facc sc[2][4] = {};
#pragma unroll
    for (int ss = 0; ss < 2; ++ss) {
      const int kcol2 = (ss * 32 + g * 8) * 2;
#pragma unroll
      for (int f = 0; f < 4; ++f) {
        int krow = f * 16 + c;
        bfrag kf = *(const bfrag*)((const char*)sK[cur] +
                                   ((krow * 128 + kcol2) ^ ((krow & 7) << 4)));
        sc[0][f] = __builtin_amdgcn_mfma_f32_16x16x32_bf16(qa[0][ss], kf, sc[0][f], 0, 0, 0);
        sc[1][f] = __builtin_amdgcn_mfma_f32_16x16x32_bf16(qa[1][ss], kf, sc[1][f], 0, 0, 0);
      }
    }

#pragma unroll
    for (int mi = 0; mi < 2; ++mi)
#pragma unroll
      for (int r = 0; r < 4; ++r) {
        float mx = fmaxf(fmaxf(sc[mi][0][r], sc[mi][1][r]), fmaxf(sc[mi][2][r], sc[mi][3][r]));
#pragma unroll
        for (int d = 1; d < 16; d <<= 1) mx = fmaxf(mx, __shfl_xor(mx, d));
        float mn = fmaxf(m_[mi][r], mx);
        float al = __expf(m_[mi][r] - mn);
        m_[mi][r] = mn;
        float sum = 0.0f;
        u16 pb[4];
#pragma unroll
        for (int f = 0; f < 4; ++f) {
          float p = __expf(sc[mi][f][r] - mn);
          pb[f] = f2bf(p);
          sum += p;
        }
#pragma unroll
        for (int d = 1; d < 16; d <<= 1) sum += __shfl_xor(sum, d);
        l_[mi][r] = l_[mi][r] * al + sum;
#pragma unroll
        for (int fo = 0; fo < 4; ++fo) o[mi][fo][r] *= al;
        int prow = mi * 16 + g * 4 + r;
#pragma unroll
        for (int f = 0; f < 4; ++f) {
          int byte_ = (prow * 128 + (f * 16 + c) * 2) ^ ((prow & 7) << 4);
          *(u16*)((char*)sP[w] + byte_) = pb[f];
        }
      }

#pragma unroll
    for (int ss = 0; ss < 2; ++ss) {
      const int kcol2 = (ss * 32 + g * 8) * 2;
      bfrag pa[2], vb[4];
#pragma unroll
      for (int mi = 0; mi < 2; ++mi) {
        int prow = mi * 16 + c;
        pa[mi] = *(const bfrag*)((const char*)sP[w] +
                                 ((prow * 128 + kcol2) ^ ((prow & 7) << 4)));
      }
#pragma unroll
      for (int fo = 0; fo < 4; ++fo) {
        int drow = fo * 16 + c;
        vb[fo] = *(const bfrag*)((const char*)sV[cur] +
                                 ((drow * 128 + kcol2) ^ ((drow & 7) << 4)));
      }
#pragma unroll
      for (int mi = 0; mi < 2; ++mi)
#pragma unroll
        for (int fo = 0; fo < 4; ++fo)
          o[mi][fo] = __builtin_amdgcn_mfma_f32_16x16x32_bf16(pa[mi], vb[fo], o[mi][fo], 0, 0, 0);
    }

    if (kb < 15) {
      stage_write(cur ^ 1);
      __syncthreads();
    }
  }

#pragma unroll
  for (int mi = 0; mi < 2; ++mi)
#pragma unroll
    for (int r = 0; r < 4; ++r) {
      float inv = 1.0f / l_[mi][r];
      long row = (long)b * 1024 + qt * 128 + w * 32 + mi * 16 + g * 4 + r;
#pragma unroll
      for (int fo = 0; fo < 4; ++fo) {
        long col = hh * 64 + fo * 16 + c;
        oh[row * 768 + col] = (f16)(o[mi][fo][r] * inv);
      }
    }
}

// ---------- host ----------
extern "C" void kernel_launch(void* const* d_in, const int* in_sizes, int n_in,
                              void* d_out, int out_size, void* d_ws, size_t ws_size,
                              hipStream_t stream) {
  const int*   x     = (const int*)d_in[0];
  const float* tok   = (const float*)d_in[1];
  const float* pos   = (const float*)d_in[2];
  const float* ln1g  = (const float*)d_in[3];
  const float* ln1b  = (const float*)d_in[4];
  const float* Wqkv  = (const float*)d_in[5];
  const float* bqkv  = (const float*)d_in[6];
  const float* Wproj = (const float*)d_in[7];
  const float* bproj = (const float*)d_in[8];
  const float* ln2g  = (const float*)d_in[9];
  const float* ln2b  = (const float*)d_in[10];
  const float* Wff1  = (const float*)d_in[11];
  const float* bff1  = (const float*)d_in[12];
  const float* Wff2  = (const float*)d_in[13];
  const float* bff2  = (const float*)d_in[14];
  const float* lnfg  = (const float*)d_in[15];
  const float* lnfb  = (const float*)d_in[16];
  float* out = (float*)d_out;

  char* p = (char*)d_ws;
  auto alloc = [&](size_t bytes) {
    char* r = p;
    p += (bytes + 255) & ~(size_t)255;
    return r;
  };
  float* h   = (float*)alloc(8192ll * 768 * 4);
  f16* a_h   = (f16*)alloc(8192ll * 768 * 2);
  u16* Qb    = (u16*)alloc(8192ll * 768 * 2);   // [B,H,T,64] bf16
  u16* Kbuf  = (u16*)alloc(8192ll * 768 * 2);
  u16* Vbuf  = (u16*)alloc(8192ll * 768 * 2);
  f16* o_h   = (f16*)alloc(8192ll * 768 * 2);
  f16* f_h   = (f16*)alloc(8192ll * 3072 * 2);
  f16* w_h   = (f16*)alloc(3072ll * 768 * 2);
  f16* t_h   = (f16*)alloc(256ll * 768 * 2);

  embed_kernel<<<6144, 256, 0, stream>>>(x, tok, pos, h);
  half_kernel<<<192, 256, 0, stream>>>(tok, t_h, 49152);

  for (int l = 0; l < 8; ++l) {
    ln_half_kernel<<<8192, 256, 0, stream>>>(h, ln1g + l * 768, ln1b + l * 768, a_h);
    thalf_kernel<<<dim3(72, 24), 256, 0, stream>>>(Wqkv + (long)l * 768 * 2304, w_h, 768, 2304);
    gemm_f16<4><<<64 * 18, 256, 0, stream>>>(a_h, w_h, 8192, 2304, 768, bqkv + l * 2304,
                                             nullptr, nullptr, nullptr, Qb, Kbuf, Vbuf);
    attn_kernel<<<768, 256, 0, stream>>>(Qb, Kbuf, Vbuf, o_h);
    thalf_kernel<<<dim3(24, 24), 256, 0, stream>>>(Wproj + (long)l * 768 * 768, w_h, 768, 768);
    gemm_f16<1><<<64 * 6, 256, 0, stream>>>(o_h, w_h, 8192, 768, 768, bproj + l * 768,
                                            h, h, nullptr, nullptr, nullptr, nullptr);
    ln_half_kernel<<<8192, 256, 0, stream>>>(h, ln2g + l * 768, ln2b + l * 768, a_h);
    thalf_kernel<<<dim3(96, 24), 256, 0, stream>>>(Wff1 + (long)l * 768 * 3072, w_h, 768, 3072);
    gemm_f16<2><<<64 * 24, 256, 0, stream>>>(a_h, w_h, 8192, 3072, 768, bff1 + l * 3072,
                                             nullptr, nullptr, f_h, nullptr, nullptr, nullptr);
    thalf_kernel<<<dim3(24, 96), 256, 0, stream>>>(Wff2 + (long)l * 3072 * 768, w_h, 3072, 768);
    gemm_f16<1><<<64 * 6, 256, 0, stream>>>(f_h, w_h, 8192, 768, 3072, bff2 + l * 768,
                                            h, h, nullptr, nullptr, nullptr, nullptr);
  }
  ln_half_kernel<<<8192, 256, 0, stream>>>(h, lnfg, lnfb, a_h);
  gemm_f16<3><<<64 * 2, 256, 0, stream>>>(a_h, t_h, 8192, 256, 768, nullptr,
                                          nullptr, out, nullptr, nullptr, nullptr, nullptr);
}

// Round 7
// 2440.633 us; speedup vs baseline: 2.1372x; 1.2000x over previous
//
#include <hip/hip_runtime.h>

typedef unsigned short u16;
typedef _Float16 f16;
typedef __attribute__((ext_vector_type(8))) _Float16 hfrag;  // 8 fp16 in 4 VGPRs
typedef __attribute__((ext_vector_type(4))) _Float16 h4;
typedef __attribute__((ext_vector_type(8))) short bfrag;     // 8 bf16
typedef __attribute__((ext_vector_type(8))) unsigned short us8;
typedef __attribute__((ext_vector_type(4))) float facc;
typedef __attribute__((ext_vector_type(16))) float facc16;

// ---------- bf16 helpers (attention path) ----------
__device__ __forceinline__ u16 f2bf(float x) {
  unsigned u = __float_as_uint(x);
  u += 0x7fffu + ((u >> 16) & 1u);
  return (u16)(u >> 16);
}
__device__ __forceinline__ float bf2f(u16 h) {
  return __uint_as_float(((unsigned)h) << 16);
}
// pack 2 f32 -> 2 bf16 in one u32 (lo <- a, hi <- b)
__device__ __forceinline__ unsigned cvtpk(float a, float b) {
  unsigned r;
  asm("v_cvt_pk_bf16_f32 %0, %1, %2" : "=v"(r) : "v"(a), "v"(b));
  return r;
}
// swap a[lanes 32-63] with b[lanes 0-31]
__device__ __forceinline__ void swap32(unsigned &a, unsigned &b) {
  asm("v_permlane32_swap_b32 %0, %1" : "+v"(a), "+v"(b));
}

// ---------- async global->LDS, 16B per lane ----------
__device__ __forceinline__ void gload16(const void* g, void* l) {
  __builtin_amdgcn_global_load_lds((const __attribute__((address_space(1))) void*)g,
                                   (__attribute__((address_space(3))) void*)l, 16, 0, 0);
}

// ---------- embedding: h = tok_emb[x] + pos_emb ----------
__global__ void embed_kernel(const int* __restrict__ x, const float* __restrict__ tok,
                             const float* __restrict__ pos, float* __restrict__ h) {
  int i = blockIdx.x * 256 + threadIdx.x;      // over 8192*192 float4
  int m = i / 192;
  int d4 = i % 192;
  int v = x[m];
  float4 t = ((const float4*)tok)[(long)v * 192 + d4];
  float4 p = ((const float4*)pos)[(long)(m & 1023) * 192 + d4];
  float4 r;
  r.x = t.x + p.x; r.y = t.y + p.y; r.z = t.z + p.z; r.w = t.w + p.w;
  ((float4*)h)[i] = r;
}

// ---------- elementwise fp32 -> fp16 (x64 scale), for tied head tok_emb ----------
__global__ void half_kernel(const float* __restrict__ in, f16* __restrict__ oh, int n4) {
  int i = blockIdx.x * 256 + threadIdx.x;
  if (i >= n4) return;
  float4 v = ((const float4*)in)[i];
  h4 r;
  r[0] = (f16)(v.x * 64.0f); r[1] = (f16)(v.y * 64.0f);
  r[2] = (f16)(v.z * 64.0f); r[3] = (f16)(v.w * 64.0f);
  ((h4*)oh)[i] = r;
}

// ---------- transpose + fp16 (x64): W[K][N] fp32 -> WT[N][K] fp16 ----------
__global__ __launch_bounds__(256)
void thalf_kernel(const float* __restrict__ W, f16* __restrict__ oh, int K, int N) {
  __shared__ float tile[32][33];
  const int tx = threadIdx.x & 31, ty = threadIdx.x >> 5;
  const long n0 = (long)blockIdx.x * 32, k0 = (long)blockIdx.y * 32;
#pragma unroll
  for (int r = 0; r < 4; ++r) {
    int kk = ty + r * 8;
    tile[kk][tx] = W[(k0 + kk) * N + n0 + tx];
  }
  __syncthreads();
#pragma unroll
  for (int r = 0; r < 4; ++r) {
    int nn = ty + r * 8;
    oh[(n0 + nn) * K + k0 + tx] = (f16)(tile[tx][nn] * 64.0f);
  }
}

// ---------- LayerNorm (D=768) -> fp16 ----------
__global__ __launch_bounds__(256)
void ln_half_kernel(const float* __restrict__ x, const float* __restrict__ gam,
                    const float* __restrict__ bet, f16* __restrict__ oh) {
  const int row = blockIdx.x, tid = threadIdx.x;
  const float* xp = x + (long)row * 768;
  float v0 = xp[tid], v1 = xp[tid + 256], v2 = xp[tid + 512];
  float s = v0 + v1 + v2;
  float q = v0 * v0 + v1 * v1 + v2 * v2;
#pragma unroll
  for (int d = 32; d > 0; d >>= 1) {
    s += __shfl_xor(s, d);
    q += __shfl_xor(q, d);
  }
  __shared__ float red[8];
  const int wave = tid >> 6, lane = tid & 63;
  if (lane == 0) { red[wave] = s; red[4 + wave] = q; }
  __syncthreads();
  s = red[0] + red[1] + red[2] + red[3];
  q = red[4] + red[5] + red[6] + red[7];
  const float mu = s * (1.0f / 768.0f);
  const float var = q * (1.0f / 768.0f) - mu * mu;
  const float rstd = rsqrtf(var + 1e-5f);
  const long base = (long)row * 768;
  oh[base + tid]       = (f16)((v0 - mu) * rstd * gam[tid] + bet[tid]);
  oh[base + tid + 256] = (f16)((v1 - mu) * rstd * gam[tid + 256] + bet[tid + 256]);
  oh[base + tid + 512] = (f16)((v2 - mu) * rstd * gam[tid + 512] + bet[tid + 512]);
}

// ---------- plain fp16 GEMM, B^T layout: C[M][N] = (A[M][K] @ BT[N][K]) / 64 ----------
// 128x128 tile, BK=64, 4 waves. global_load_lds staging, pre-swizzled source.
// EPI: 1 = +bias+res -> f32 ; 2 = +bias, GELU -> fp16 ; 3 = plain -> f32 ;
//      4 = +bias -> bf16 scattered to Q/K/V [B,H,T,64]
template <int EPI>
__global__ __launch_bounds__(256, 3)
void gemm_f16(const f16* __restrict__ A, const f16* __restrict__ B,
              int M, int N, int K, const float* __restrict__ bias,
              const float* res, float* outf, f16* outh,
              u16* outq, u16* outk, u16* outv) {
  __shared__ f16 lds[2 * 128 * 64];          // 32 KB: A tile, B tile
  f16* sA = lds;
  f16* sB = lds + 8192;

  const int tid = threadIdx.x;
  const int lane = tid & 63, wave = tid >> 6;
  const int g = lane >> 4, c = lane & 15;
  const int nb = N >> 7;
  const int nwg = gridDim.x;
  const int swz = (blockIdx.x & 7) * (nwg >> 3) + (blockIdx.x >> 3);  // XCD swizzle (nwg%8==0)
  const int mt = swz / nb, nt = swz % nb;
  const long m0 = (long)mt << 7, n0 = (long)nt << 7;
  const int wm = (wave >> 1) << 6, wn = (wave & 1) << 6;

  facc acc[4][4] = {};

  int arow[4], brow[4];
#pragma unroll
  for (int i = 0; i < 4; ++i) {
    arow[i] = wm + i * 16 + c;
    brow[i] = wn + i * 16 + c;
  }

  const int nkt = K >> 6;
  for (int kt = 0; kt < nkt; ++kt) {
    __syncthreads();
    {
      const long kcol = (long)kt * 64;
#pragma unroll
      for (int i = 0; i < 4; ++i) {
        const int ci = (wave * 4 + i) * 64 + lane;
        const int row = ci >> 3;
        const int slot = (ci & 7) ^ (row & 7);
        const long ga = (m0 + row) * (long)K + kcol + slot * 8;
        const long gb = (n0 + row) * (long)K + kcol + slot * 8;
        const int lb = (wave * 4 + i) * 512;
        gload16(A + ga, sA + lb);
        gload16(B + gb, sB + lb);
      }
    }
    __syncthreads();
#pragma unroll
    for (int ks = 0; ks < 2; ++ks) {
      const int kb = (ks * 32 + g * 8) * 2;
      hfrag ah[4], bh[4];
#pragma unroll
      for (int i = 0; i < 4; ++i) {
        int ab = arow[i] * 128 + (kb ^ ((arow[i] & 7) << 4));
        ah[i] = *(const hfrag*)((const char*)sA + ab);
        int bb = brow[i] * 128 + (kb ^ ((brow[i] & 7) << 4));
        bh[i] = *(const hfrag*)((const char*)sB + bb);
      }
#pragma unroll
      for (int mi = 0; mi < 4; ++mi)
#pragma unroll
        for (int ni = 0; ni < 4; ++ni)
          acc[mi][ni] = __builtin_amdgcn_mfma_f32_16x16x32_f16(ah[mi], bh[ni], acc[mi][ni], 0, 0, 0);
    }
  }

#pragma unroll
  for (int mi = 0; mi < 4; ++mi)
#pragma unroll
    for (int ni = 0; ni < 4; ++ni)
#pragma unroll
      for (int r = 0; r < 4; ++r) {
        long row = m0 + wm + mi * 16 + g * 4 + r;
        long col = n0 + wn + ni * 16 + c;
        float v = acc[mi][ni][r] * 0.015625f;            // undo x64 weight scale
        if (EPI == 1) {
          outf[row * N + col] = v + bias[col] + res[row * N + col];
        } else if (EPI == 2) {
          v += bias[col];
          v = 0.5f * v * (1.0f + erff(v * 0.70710678118654752f));
          outh[row * N + col] = (f16)v;
        } else if (EPI == 4) {
          v += bias[col];
          int sc_ = (int)col;
          u16* dst;
          if (sc_ >= 1536) { dst = outv; sc_ -= 1536; }
          else if (sc_ >= 768) { dst = outk; sc_ -= 768; }
          else dst = outq;
          int hh = sc_ >> 6, dd = sc_ & 63;
          long addr = ((((row >> 10) * 12 + hh) << 10) + (row & 1023)) * 64 + dd;
          dst[addr] = f2bf(v);
        } else {
          outf[row * N + col] = v;
        }
      }
}

// ---------- fused flash attention v3: swapped 32x32 QK^T, in-register softmax ----------
// grid 768 (XCD-swizzled: each XCD owns one batch sample's 12 heads -> KV L2-resident).
// Per wave: 32 q-rows, q = lane&31 is LANE-LOCAL through softmax AND PV (D[d][q]).
// P->bf16 fragments fully in-register: 16 cvt_pk + 8 permlane32_swap (T12).
// LDS: K[64][64] + V^T[64][64], double-buffered, XOR-swizzled, no P tile. 32 KB.
__global__ __launch_bounds__(256, 2)
void attn_kernel(const u16* __restrict__ Qb, const u16* __restrict__ Kb,
                 const u16* __restrict__ Vb, f16* __restrict__ oh) {
  __shared__ u16 sK[2][4096];        // [key][d] swizzled: byte (key*128+d*2)^((key&7)<<4)
  __shared__ u16 sVT[2][4096];       // V^T [d][key] swizzled: byte (d*128+k*2)^((d&7)<<4)
  const int tid = threadIdx.x;
  const int lane = tid & 63, w = tid >> 6;
  const int hi = lane >> 5, q = lane & 31;
  const int swz = (blockIdx.x & 7) * 96 + (blockIdx.x >> 3);
  const int qt = swz & 7, bh = swz >> 3;
  const int b = bh / 12, hh = bh % 12;
  const long kvbase = (long)bh * 1024 * 64;

  // Q as B-operand fragments (col q = lane&31, d-slot = 16s+8hi+j), pre-scaled 0.125
  bfrag qb[4];
  const int qrow = qt * 128 + w * 32 + q;
  {
    const u16* qp = Qb + kvbase + (long)qrow * 64;
#pragma unroll
    for (int s = 0; s < 4; ++s) {
      us8 t = *(const us8*)(qp + s * 16 + hi * 8);
      bfrag tmp;
#pragma unroll
      for (int j = 0; j < 8; ++j) tmp[j] = (short)f2bf(bf2f(t[j]) * 0.125f);
      qb[s] = tmp;
    }
  }

  facc16 o[2] = {};                  // D[d][q]: dt 0/1 -> d = 32*dt + crow(reg,hi)
  float m_ = -1e30f, l_ = 0.0f;

  // staging: K rows via us8 (conflict-free as before); V transposed via packed u32
  const int kr0 = tid >> 3, sl = tid & 7;          // K rows kr0, kr0+32
  const int vm = tid & 31, vs = tid >> 5;          // V rows 2vm,2vm+1, d-slot vs
  us8 kreg0, kreg1, vreg0, vreg1;

  auto stage_load = [&](int kb) {
    const u16* kp = Kb + kvbase + (long)kb * 4096;
    const u16* vp = Vb + kvbase + (long)kb * 4096;
    kreg0 = *(const us8*)(kp + kr0 * 64 + sl * 8);
    kreg1 = *(const us8*)(kp + (kr0 + 32) * 64 + sl * 8);
    vreg0 = *(const us8*)(vp + (2 * vm) * 64 + vs * 8);
    vreg1 = *(const us8*)(vp + (2 * vm + 1) * 64 + vs * 8);
  };
  auto stage_write = [&](int buf) {
    *(us8*)((char*)sK[buf] + ((kr0 * 128 + sl * 16) ^ ((kr0 & 7) << 4))) = kreg0;
    const int kr1 = kr0 + 32;
    *(us8*)((char*)sK[buf] + ((kr1 * 128 + sl * 16) ^ ((kr1 & 7) << 4))) = kreg1;
#pragma unroll
    for (int j = 0; j < 8; ++j) {                  // V^T[d][2vm..2vm+1] as one u32
      int d = vs * 8 + j;                          // bank = vm ^ 4j -> 2-way (free)
      unsigned pk = (unsigned)(u16)vreg0[j] | ((unsigned)(u16)vreg1[j] << 16);
      *(unsigned*)((char*)sVT[buf] + ((d * 128 + vm * 4) ^ ((d & 7) << 4))) = pk;
    }
  };

  stage_load(0);
  stage_write(0);
  __syncthreads();

  for (int kb = 0; kb < 16; ++kb) {
    const int cur = kb & 1;
    if (kb < 15) stage_load(kb + 1);               // issue early, write after barrier

    // S = K Q^T (A=K rows=key, B=Q cols=q): D[key][q], q = lane&31 lane-local
    facc16 sc[2] = {};
#pragma unroll
    for (int s = 0; s < 4; ++s) {
      const int off = 32 * s + 16 * hi;
      bfrag k0 = *(const bfrag*)((const char*)sK[cur] + ((q * 128 + off) ^ ((q & 7) << 4)));
      bfrag k1 = *(const bfrag*)((const char*)sK[cur] + (((q + 32) * 128 + off) ^ ((q & 7) << 4)));
      sc[0] = __builtin_amdgcn_mfma_f32_32x32x16_bf16(k0, qb[s], sc[0], 0, 0, 0);
      sc[1] = __builtin_amdgcn_mfma_f32_32x32x16_bf16(k1, qb[s], sc[1], 0, 0, 0);
    }

    // in-register online softmax for q = lane&31 (32 keys here + 32 on partner lane)
    float mx = sc[0][0];
#pragma unroll
    for (int r = 1; r < 16; ++r) mx = fmaxf(mx, sc[0][r]);
#pragma unroll
    for (int r = 0; r < 16; ++r) mx = fmaxf(mx, sc[1][r]);
    mx = fmaxf(mx, __shfl_xor(mx, 32));
    const float mn = fmaxf(m_, mx);
    const float al = __expf(m_ - mn);
    m_ = mn;
    float sum = 0.0f;
#pragma unroll
    for (int kt = 0; kt < 2; ++kt)
#pragma unroll
      for (int r = 0; r < 16; ++r) {
        float pv = __expf(sc[kt][r] - mn);
        sc[kt][r] = pv;
        sum += pv;
      }
    sum += __shfl_xor(sum, 32);
    l_ = l_ * al + sum;
#pragma unroll
    for (int r = 0; r < 16; ++r) { o[0][r] *= al; o[1][r] *= al; }

    // O += V^T P^T : per ks build P fragment in-register (cvt_pk + permlane32_swap)
#pragma unroll
    for (int ks = 0; ks < 4; ++ks) {
      const int kt = ks >> 1, rb = (ks & 1) * 8;
      unsigned w0 = cvtpk(sc[kt][rb + 0], sc[kt][rb + 1]);
      unsigned w1 = cvtpk(sc[kt][rb + 2], sc[kt][rb + 3]);
      unsigned w2 = cvtpk(sc[kt][rb + 4], sc[kt][rb + 5]);
      unsigned w3 = cvtpk(sc[kt][rb + 6], sc[kt][rb + 7]);
      swap32(w0, w2);                              // exchange hi'-halves with partner
      swap32(w1, w3);
      union { unsigned u[4]; bfrag f; } pa;
      pa.u[0] = w0; pa.u[1] = w1; pa.u[2] = w2; pa.u[3] = w3;
      const int off = 32 * ks + 16 * hi;
      bfrag v0 = *(const bfrag*)((const char*)sVT[cur] + ((q * 128 + off) ^ ((q & 7) << 4)));
      bfrag v1 = *(const bfrag*)((const char*)sVT[cur] + (((q + 32) * 128 + off) ^ ((q & 7) << 4)));
      o[0] = __builtin_amdgcn_mfma_f32_32x32x16_bf16(v0, pa.f, o[0], 0, 0, 0);
      o[1] = __builtin_amdgcn_mfma_f32_32x32x16_bf16(v1, pa.f, o[1], 0, 0, 0);
    }

    if (kb < 15) {
      stage_write(cur ^ 1);
      __syncthreads();
    }
  }

  // epilogue: lane q = lane&31, d = 32*dt + (reg&3) + 8*(reg>>2) + 4*hi
  const float inv = 1.0f / l_;
  const long row = (long)b * 1024 + qrow;
  f16* op = oh + row * 768 + hh * 64;
#pragma unroll
  for (int dt = 0; dt < 2; ++dt)
#pragma unroll
    for (int r = 0; r < 16; ++r) {
      int d = 32 * dt + (r & 3) + 8 * (r >> 2) + 4 * hi;
      op[d] = (f16)(o[dt][r] * inv);
    }
}

// ---------- host ----------
extern "C" void kernel_launch(void* const* d_in, const int* in_sizes, int n_in,
                              void* d_out, int out_size, void* d_ws, size_t ws_size,
                              hipStream_t stream) {
  const int*   x     = (const int*)d_in[0];
  const float* tok   = (const float*)d_in[1];
  const float* pos   = (const float*)d_in[2];
  const float* ln1g  = (const float*)d_in[3];
  const float* ln1b  = (const float*)d_in[4];
  const float* Wqkv  = (const float*)d_in[5];
  const float* bqkv  = (const float*)d_in[6];
  const float* Wproj = (const float*)d_in[7];
  const float* bproj = (const float*)d_in[8];
  const float* ln2g  = (const float*)d_in[9];
  const float* ln2b  = (const float*)d_in[10];
  const float* Wff1  = (const float*)d_in[11];
  const float* bff1  = (const float*)d_in[12];
  const float* Wff2  = (const float*)d_in[13];
  const float* bff2  = (const float*)d_in[14];
  const float* lnfg  = (const float*)d_in[15];
  const float* lnfb  = (const float*)d_in[16];
  float* out = (float*)d_out;

  char* p = (char*)d_ws;
  auto alloc = [&](size_t bytes) {
    char* r = p;
    p += (bytes + 255) & ~(size_t)255;
    return r;
  };
  float* h   = (float*)alloc(8192ll * 768 * 4);
  f16* a_h   = (f16*)alloc(8192ll * 768 * 2);
  u16* Qb    = (u16*)alloc(8192ll * 768 * 2);   // [B,H,T,64] bf16
  u16* Kbuf  = (u16*)alloc(8192ll * 768 * 2);
  u16* Vbuf  = (u16*)alloc(8192ll * 768 * 2);
  f16* o_h   = (f16*)alloc(8192ll * 768 * 2);
  f16* f_h   = (f16*)alloc(8192ll * 3072 * 2);
  f16* w_h   = (f16*)alloc(3072ll * 768 * 2);
  f16* t_h   = (f16*)alloc(256ll * 768 * 2);

  embed_kernel<<<6144, 256, 0, stream>>>(x, tok, pos, h);
  half_kernel<<<192, 256, 0, stream>>>(tok, t_h, 49152);

  for (int l = 0; l < 8; ++l) {
    ln_half_kernel<<<8192, 256, 0, stream>>>(h, ln1g + l * 768, ln1b + l * 768, a_h);
    thalf_kernel<<<dim3(72, 24), 256, 0, stream>>>(Wqkv + (long)l * 768 * 2304, w_h, 768, 2304);
    gemm_f16<4><<<64 * 18, 256, 0, stream>>>(a_h, w_h, 8192, 2304, 768, bqkv + l * 2304,
                                             nullptr, nullptr, nullptr, Qb, Kbuf, Vbuf);
    attn_kernel<<<768, 256, 0, stream>>>(Qb, Kbuf, Vbuf, o_h);
    thalf_kernel<<<dim3(24, 24), 256, 0, stream>>>(Wproj + (long)l * 768 * 768, w_h, 768, 768);
    gemm_f16<1><<<64 * 6, 256, 0, stream>>>(o_h, w_h, 8192, 768, 768, bproj + l * 768,
                                            h, h, nullptr, nullptr, nullptr, nullptr);
    ln_half_kernel<<<8192, 256, 0, stream>>>(h, ln2g + l * 768, ln2b + l * 768, a_h);
    thalf_kernel<<<dim3(96, 24), 256, 0, stream>>>(Wff1 + (long)l * 768 * 3072, w_h, 768, 3072);
    gemm_f16<2><<<64 * 24, 256, 0, stream>>>(a_h, w_h, 8192, 3072, 768, bff1 + l * 3072,
                                             nullptr, nullptr, f_h, nullptr, nullptr, nullptr);
    thalf_kernel<<<dim3(24, 96), 256, 0, stream>>>(Wff2 + (long)l * 3072 * 768, w_h, 3072, 768);
    gemm_f16<1><<<64 * 6, 256, 0, stream>>>(f_h, w_h, 8192, 768, 3072, bff2 + l * 768,
                                            h, h, nullptr, nullptr, nullptr, nullptr);
  }
  ln_half_kernel<<<8192, 256, 0, stream>>>(h, lnfg, lnfb, a_h);
  gemm_f16<3><<<64 * 2, 256, 0, stream>>>(a_h, t_h, 8192, 256, 768, nullptr,
                                          nullptr, out, nullptr, nullptr, nullptr, nullptr);
}

// Round 10
// 2337.555 us; speedup vs baseline: 2.2314x; 1.0441x over previous
//
#include <hip/hip_runtime.h>

typedef unsigned short u16;
typedef _Float16 f16;
typedef __attribute__((ext_vector_type(8))) _Float16 hfrag;  // 8 fp16 in 4 VGPRs
typedef __attribute__((ext_vector_type(4))) _Float16 h4;
typedef __attribute__((ext_vector_type(8))) short bfrag;     // 8 bf16
typedef __attribute__((ext_vector_type(8))) unsigned short us8;
typedef __attribute__((ext_vector_type(4))) float facc;
typedef __attribute__((ext_vector_type(16))) float facc16;

// ---------- bf16 helpers (attention path) ----------
__device__ __forceinline__ u16 f2bf(float x) {
  unsigned u = __float_as_uint(x);
  u += 0x7fffu + ((u >> 16) & 1u);
  return (u16)(u >> 16);
}
__device__ __forceinline__ float bf2f(u16 h) {
  return __uint_as_float(((unsigned)h) << 16);
}
// pack 2 f32 -> 2 bf16 in one u32 (lo <- a, hi <- b)
__device__ __forceinline__ unsigned cvtpk(float a, float b) {
  unsigned r;
  asm("v_cvt_pk_bf16_f32 %0, %1, %2" : "=v"(r) : "v"(a), "v"(b));
  return r;
}
// swap a[lanes 32-63] with b[lanes 0-31]
__device__ __forceinline__ void swap32(unsigned &a, unsigned &b) {
  asm("v_permlane32_swap_b32 %0, %1" : "+v"(a), "+v"(b));
}

// ---------- async global->LDS, 16B per lane ----------
__device__ __forceinline__ void gload16(const void* g, void* l) {
  __builtin_amdgcn_global_load_lds((const __attribute__((address_space(1))) void*)g,
                                   (__attribute__((address_space(3))) void*)l, 16, 0, 0);
}

// ---------- embedding: h = tok_emb[x] + pos_emb ----------
__global__ void embed_kernel(const int* __restrict__ x, const float* __restrict__ tok,
                             const float* __restrict__ pos, float* __restrict__ h) {
  int i = blockIdx.x * 256 + threadIdx.x;      // over 8192*192 float4
  int m = i / 192;
  int d4 = i % 192;
  int v = x[m];
  float4 t = ((const float4*)tok)[(long)v * 192 + d4];
  float4 p = ((const float4*)pos)[(long)(m & 1023) * 192 + d4];
  float4 r;
  r.x = t.x + p.x; r.y = t.y + p.y; r.z = t.z + p.z; r.w = t.w + p.w;
  ((float4*)h)[i] = r;
}

// ---------- elementwise fp32 -> fp16 (x64 scale), for tied head tok_emb ----------
__global__ void half_kernel(const float* __restrict__ in, f16* __restrict__ oh, int n4) {
  int i = blockIdx.x * 256 + threadIdx.x;
  if (i >= n4) return;
  float4 v = ((const float4*)in)[i];
  h4 r;
  r[0] = (f16)(v.x * 64.0f); r[1] = (f16)(v.y * 64.0f);
  r[2] = (f16)(v.z * 64.0f); r[3] = (f16)(v.w * 64.0f);
  ((h4*)oh)[i] = r;
}

// ---------- transpose + fp16 (x64): W[K][N] fp32 -> WT[N][K] fp16 ----------
__global__ __launch_bounds__(256)
void thalf_kernel(const float* __restrict__ W, f16* __restrict__ oh, int K, int N) {
  __shared__ float tile[32][33];
  const int tx = threadIdx.x & 31, ty = threadIdx.x >> 5;
  const long n0 = (long)blockIdx.x * 32, k0 = (long)blockIdx.y * 32;
#pragma unroll
  for (int r = 0; r < 4; ++r) {
    int kk = ty + r * 8;
    tile[kk][tx] = W[(k0 + kk) * N + n0 + tx];
  }
  __syncthreads();
#pragma unroll
  for (int r = 0; r < 4; ++r) {
    int nn = ty + r * 8;
    oh[(n0 + nn) * K + k0 + tx] = (f16)(tile[tx][nn] * 64.0f);
  }
}

// ---------- LayerNorm (D=768) -> fp16 ----------
__global__ __launch_bounds__(256)
void ln_half_kernel(const float* __restrict__ x, const float* __restrict__ gam,
                    const float* __restrict__ bet, f16* __restrict__ oh) {
  const int row = blockIdx.x, tid = threadIdx.x;
  const float* xp = x + (long)row * 768;
  float v0 = xp[tid], v1 = xp[tid + 256], v2 = xp[tid + 512];
  float s = v0 + v1 + v2;
  float q = v0 * v0 + v1 * v1 + v2 * v2;
#pragma unroll
  for (int d = 32; d > 0; d >>= 1) {
    s += __shfl_xor(s, d);
    q += __shfl_xor(q, d);
  }
  __shared__ float red[8];
  const int wave = tid >> 6, lane = tid & 63;
  if (lane == 0) { red[wave] = s; red[4 + wave] = q; }
  __syncthreads();
  s = red[0] + red[1] + red[2] + red[3];
  q = red[4] + red[5] + red[6] + red[7];
  const float mu = s * (1.0f / 768.0f);
  const float var = q * (1.0f / 768.0f) - mu * mu;
  const float rstd = rsqrtf(var + 1e-5f);
  const long base = (long)row * 768;
  oh[base + tid]       = (f16)((v0 - mu) * rstd * gam[tid] + bet[tid]);
  oh[base + tid + 256] = (f16)((v1 - mu) * rstd * gam[tid + 256] + bet[tid + 256]);
  oh[base + tid + 512] = (f16)((v2 - mu) * rstd * gam[tid + 512] + bet[tid + 512]);
}

// ---------- plain fp16 GEMM, B^T layout: C[M][N] = (A[M][K] @ BT[N][K]) / 64 ----------
// 128x128 tile, BK=64, 4 waves. Double-buffered LDS + global_load_lds width=16:
// STAGE(kt+1) issues BEFORE compute(kt); single barrier per K-tile (T3-minimum).
// Pre-swizzled global source keeps the XOR read layout.
// EPI: 1 = +bias+res -> f32 ; 2 = +bias, GELU -> fp16 ; 3 = plain -> f32 ;
//      4 = +bias -> bf16 scattered to Q/K/V [B,H,T,64]
template <int EPI>
__global__ __launch_bounds__(256, 2)
void gemm_f16(const f16* __restrict__ A, const f16* __restrict__ B,
              int M, int N, int K, const float* __restrict__ bias,
              const float* res, float* outf, f16* outh,
              u16* outq, u16* outk, u16* outv) {
  __shared__ f16 lds[4 * 8192];              // 64 KB: A0, A1, B0, B1 tiles

  const int tid = threadIdx.x;
  const int lane = tid & 63, wave = tid >> 6;
  const int g = lane >> 4, c = lane & 15;
  const int nb = N >> 7;
  const int nwg = gridDim.x;
  const int swz = (blockIdx.x & 7) * (nwg >> 3) + (blockIdx.x >> 3);  // XCD swizzle (nwg%8==0)
  const int mt = swz / nb, nt = swz % nb;
  const long m0 = (long)mt << 7, n0 = (long)nt << 7;
  const int wm = (wave >> 1) << 6, wn = (wave & 1) << 6;

  facc acc[4][4] = {};

  int arow[4], brow[4];
#pragma unroll
  for (int i = 0; i < 4; ++i) {
    arow[i] = wm + i * 16 + c;
    brow[i] = wn + i * 16 + c;
  }

  auto STAGE = [&](int kt, int buf) {
    const long kcol = (long)kt * 64;
    f16* dA = lds + buf * 8192;
    f16* dB = lds + 16384 + buf * 8192;
#pragma unroll
    for (int i = 0; i < 4; ++i) {
      const int ci = (wave * 4 + i) * 64 + lane;       // chunk 0..1023
      const int row = ci >> 3;
      const int slot = (ci & 7) ^ (row & 7);           // pre-swizzled source slot
      const long ga = (m0 + row) * (long)K + kcol + slot * 8;
      const long gb = (n0 + row) * (long)K + kcol + slot * 8;
      const int lb = (wave * 4 + i) * 512;             // wave-uniform LDS base (f16)
      gload16(A + ga, dA + lb);
      gload16(B + gb, dB + lb);
    }
  };

  const int nkt = K >> 6;
  STAGE(0, 0);
  __syncthreads();                            // drain vmcnt(0): tile 0 landed
  for (int kt = 0; kt < nkt; ++kt) {
    const int cur = kt & 1;
    if (kt + 1 < nkt) STAGE(kt + 1, cur ^ 1); // async: overlaps compute below
    const f16* sA = lds + cur * 8192;
    const f16* sB = lds + 16384 + cur * 8192;
#pragma unroll
    for (int ks = 0; ks < 2; ++ks) {
      const int kb = (ks * 32 + g * 8) * 2;
      hfrag ah[4], bh[4];
#pragma unroll
      for (int i = 0; i < 4; ++i) {
        int ab = arow[i] * 128 + (kb ^ ((arow[i] & 7) << 4));
        ah[i] = *(const hfrag*)((const char*)sA + ab);
        int bb = brow[i] * 128 + (kb ^ ((brow[i] & 7) << 4));
        bh[i] = *(const hfrag*)((const char*)sB + bb);
      }
#pragma unroll
      for (int mi = 0; mi < 4; ++mi)
#pragma unroll
        for (int ni = 0; ni < 4; ++ni)
          acc[mi][ni] = __builtin_amdgcn_mfma_f32_16x16x32_f16(ah[mi], bh[ni], acc[mi][ni], 0, 0, 0);
    }
    __syncthreads();   // drains next-tile DMA (residual latency) + protects cur^1 reuse
  }

#pragma unroll
  for (int mi = 0; mi < 4; ++mi)
#pragma unroll
    for (int ni = 0; ni < 4; ++ni)
#pragma unroll
      for (int r = 0; r < 4; ++r) {
        long row = m0 + wm + mi * 16 + g * 4 + r;
        long col = n0 + wn + ni * 16 + c;
        float v = acc[mi][ni][r] * 0.015625f;            // undo x64 weight scale
        if (EPI == 1) {
          outf[row * N + col] = v + bias[col] + res[row * N + col];
        } else if (EPI == 2) {
          v += bias[col];
          v = 0.5f * v * (1.0f + erff(v * 0.70710678118654752f));
          outh[row * N + col] = (f16)v;
        } else if (EPI == 4) {
          v += bias[col];
          int sc_ = (int)col;
          u16* dst;
          if (sc_ >= 1536) { dst = outv; sc_ -= 1536; }
          else if (sc_ >= 768) { dst = outk; sc_ -= 768; }
          else dst = outq;
          int hh = sc_ >> 6, dd = sc_ & 63;
          long addr = ((((row >> 10) * 12 + hh) << 10) + (row & 1023)) * 64 + dd;
          dst[addr] = f2bf(v);
        } else {
          outf[row * N + col] = v;
        }
      }
}

// ---------- fused flash attention v3: swapped 32x32 QK^T, in-register softmax ----------
// grid 768 (XCD-swizzled: each XCD owns one batch sample's 12 heads -> KV L2-resident).
// Per wave: 32 q-rows, q = lane&31 is LANE-LOCAL through softmax AND PV (D[d][q]).
// P->bf16 fragments fully in-register: 16 cvt_pk + 8 permlane32_swap (T12).
// LDS: K[64][64] + V^T[64][64], double-buffered, XOR-swizzled, no P tile. 32 KB.
__global__ __launch_bounds__(256, 2)
void attn_kernel(const u16* __restrict__ Qb, const u16* __restrict__ Kb,
                 const u16* __restrict__ Vb, f16* __restrict__ oh) {
  __shared__ u16 sK[2][4096];        // [key][d] swizzled: byte (key*128+d*2)^((key&7)<<4)
  __shared__ u16 sVT[2][4096];       // V^T [d][key] swizzled: byte (d*128+k*2)^((d&7)<<4)
  const int tid = threadIdx.x;
  const int lane = tid & 63, w = tid >> 6;
  const int hi = lane >> 5, q = lane & 31;
  const int swz = (blockIdx.x & 7) * 96 + (blockIdx.x >> 3);
  const int qt = swz & 7, bh = swz >> 3;
  const int b = bh / 12, hh = bh % 12;
  const long kvbase = (long)bh * 1024 * 64;

  // Q as B-operand fragments (col q = lane&31, d-slot = 16s+8hi+j), pre-scaled 0.125
  bfrag qb[4];
  const int qrow = qt * 128 + w * 32 + q;
  {
    const u16* qp = Qb + kvbase + (long)qrow * 64;
#pragma unroll
    for (int s = 0; s < 4; ++s) {
      us8 t = *(const us8*)(qp + s * 16 + hi * 8);
      bfrag tmp;
#pragma unroll
      for (int j = 0; j < 8; ++j) tmp[j] = (short)f2bf(bf2f(t[j]) * 0.125f);
      qb[s] = tmp;
    }
  }

  facc16 o[2] = {};                  // D[d][q]: dt 0/1 -> d = 32*dt + crow(reg,hi)
  float m_ = -1e30f, l_ = 0.0f;

  const int kr0 = tid >> 3, sl = tid & 7;          // K rows kr0, kr0+32
  const int vm = tid & 31, vs = tid >> 5;          // V rows 2vm,2vm+1, d-slot vs
  us8 kreg0, kreg1, vreg0, vreg1;

  auto stage_load = [&](int kb) {
    const u16* kp = Kb + kvbase + (long)kb * 4096;
    const u16* vp = Vb + kvbase + (long)kb * 4096;
    kreg0 = *(const us8*)(kp + kr0 * 64 + sl * 8);
    kreg1 = *(const us8*)(kp + (kr0 + 32) * 64 + sl * 8);
    vreg0 = *(const us8*)(vp + (2 * vm) * 64 + vs * 8);
    vreg1 = *(const us8*)(vp + (2 * vm + 1) * 64 + vs * 8);
  };
  auto stage_write = [&](int buf) {
    *(us8*)((char*)sK[buf] + ((kr0 * 128 + sl * 16) ^ ((kr0 & 7) << 4))) = kreg0;
    const int kr1 = kr0 + 32;
    *(us8*)((char*)sK[buf] + ((kr1 * 128 + sl * 16) ^ ((kr1 & 7) << 4))) = kreg1;
#pragma unroll
    for (int j = 0; j < 8; ++j) {                  // V^T[d][2vm..2vm+1] as one u32
      int d = vs * 8 + j;                          // bank = vm ^ 4j -> 2-way (free)
      unsigned pk = (unsigned)(u16)vreg0[j] | ((unsigned)(u16)vreg1[j] << 16);
      *(unsigned*)((char*)sVT[buf] + ((d * 128 + vm * 4) ^ ((d & 7) << 4))) = pk;
    }
  };

  stage_load(0);
  stage_write(0);
  __syncthreads();

  for (int kb = 0; kb < 16; ++kb) {
    const int cur = kb & 1;
    if (kb < 15) stage_load(kb + 1);               // issue early, write after barrier

    // S = K Q^T (A=K rows=key, B=Q cols=q): D[key][q], q = lane&31 lane-local
    facc16 sc[2] = {};
#pragma unroll
    for (int s = 0; s < 4; ++s) {
      const int off = 32 * s + 16 * hi;
      bfrag k0 = *(const bfrag*)((const char*)sK[cur] + ((q * 128 + off) ^ ((q & 7) << 4)));
      bfrag k1 = *(const bfrag*)((const char*)sK[cur] + (((q + 32) * 128 + off) ^ ((q & 7) << 4)));
      sc[0] = __builtin_amdgcn_mfma_f32_32x32x16_bf16(k0, qb[s], sc[0], 0, 0, 0);
      sc[1] = __builtin_amdgcn_mfma_f32_32x32x16_bf16(k1, qb[s], sc[1], 0, 0, 0);
    }

    // in-register online softmax for q = lane&31 (32 keys here + 32 on partner lane)
    float mx = sc[0][0];
#pragma unroll
    for (int r = 1; r < 16; ++r) mx = fmaxf(mx, sc[0][r]);
#pragma unroll
    for (int r = 0; r < 16; ++r) mx = fmaxf(mx, sc[1][r]);
    mx = fmaxf(mx, __shfl_xor(mx, 32));
    const float mn = fmaxf(m_, mx);
    const float al = __expf(m_ - mn);
    m_ = mn;
    float sum = 0.0f;
#pragma unroll
    for (int kt = 0; kt < 2; ++kt)
#pragma unroll
      for (int r = 0; r < 16; ++r) {
        float pv = __expf(sc[kt][r] - mn);
        sc[kt][r] = pv;
        sum += pv;
      }
    sum += __shfl_xor(sum, 32);
    l_ = l_ * al + sum;
#pragma unroll
    for (int r = 0; r < 16; ++r) { o[0][r] *= al; o[1][r] *= al; }

    // O += V^T P^T : per ks build P fragment in-register (cvt_pk + permlane32_swap)
#pragma unroll
    for (int ks = 0; ks < 4; ++ks) {
      const int kt = ks >> 1, rb = (ks & 1) * 8;
      unsigned w0 = cvtpk(sc[kt][rb + 0], sc[kt][rb + 1]);
      unsigned w1 = cvtpk(sc[kt][rb + 2], sc[kt][rb + 3]);
      unsigned w2 = cvtpk(sc[kt][rb + 4], sc[kt][rb + 5]);
      unsigned w3 = cvtpk(sc[kt][rb + 6], sc[kt][rb + 7]);
      swap32(w0, w2);                              // exchange hi'-halves with partner
      swap32(w1, w3);
      union { unsigned u[4]; bfrag f; } pa;
      pa.u[0] = w0; pa.u[1] = w1; pa.u[2] = w2; pa.u[3] = w3;
      const int off = 32 * ks + 16 * hi;
      bfrag v0 = *(const bfrag*)((const char*)sVT[cur] + ((q * 128 + off) ^ ((q & 7) << 4)));
      bfrag v1 = *(const bfrag*)((const char*)sVT[cur] + (((q + 32) * 128 + off) ^ ((q & 7) << 4)));
      o[0] = __builtin_amdgcn_mfma_f32_32x32x16_bf16(v0, pa.f, o[0], 0, 0, 0);
      o[1] = __builtin_amdgcn_mfma_f32_32x32x16_bf16(v1, pa.f, o[1], 0, 0, 0);
    }

    if (kb < 15) {
      stage_write(cur ^ 1);
      __syncthreads();
    }
  }

  // epilogue: lane q = lane&31, d = 32*dt + (reg&3) + 8*(reg>>2) + 4*hi
  const float inv = 1.0f / l_;
  const long row = (long)b * 1024 + qrow;
  f16* op = oh + row * 768 + hh * 64;
#pragma unroll
  for (int dt = 0; dt < 2; ++dt)
#pragma unroll
    for (int r = 0; r < 16; ++r) {
      int d = 32 * dt + (r & 3) + 8 * (r >> 2) + 4 * hi;
      op[d] = (f16)(o[dt][r] * inv);
    }
}

// ---------- host ----------
extern "C" void kernel_launch(void* const* d_in, const int* in_sizes, int n_in,
                              void* d_out, int out_size, void* d_ws, size_t ws_size,
                              hipStream_t stream) {
  const int*   x     = (const int*)d_in[0];
  const float* tok   = (const float*)d_in[1];
  const float* pos   = (const float*)d_in[2];
  const float* ln1g  = (const float*)d_in[3];
  const float* ln1b  = (const float*)d_in[4];
  const float* Wqkv  = (const float*)d_in[5];
  const float* bqkv  = (const float*)d_in[6];
  const float* Wproj = (const float*)d_in[7];
  const float* bproj = (const float*)d_in[8];
  const float* ln2g  = (const float*)d_in[9];
  const float* ln2b  = (const float*)d_in[10];
  const float* Wff1  = (const float*)d_in[11];
  const float* bff1  = (const float*)d_in[12];
  const float* Wff2  = (const float*)d_in[13];
  const float* bff2  = (const float*)d_in[14];
  const float* lnfg  = (const float*)d_in[15];
  const float* lnfb  = (const float*)d_in[16];
  float* out = (float*)d_out;

  char* p = (char*)d_ws;
  auto alloc = [&](size_t bytes) {
    char* r = p;
    p += (bytes + 255) & ~(size_t)255;
    return r;
  };
  float* h   = (float*)alloc(8192ll * 768 * 4);
  f16* a_h   = (f16*)alloc(8192ll * 768 * 2);
  u16* Qb    = (u16*)alloc(8192ll * 768 * 2);   // [B,H,T,64] bf16
  u16* Kbuf  = (u16*)alloc(8192ll * 768 * 2);
  u16* Vbuf  = (u16*)alloc(8192ll * 768 * 2);
  f16* o_h   = (f16*)alloc(8192ll * 768 * 2);
  f16* f_h   = (f16*)alloc(8192ll * 3072 * 2);
  f16* w_h   = (f16*)alloc(3072ll * 768 * 2);
  f16* t_h   = (f16*)alloc(256ll * 768 * 2);

  embed_kernel<<<6144, 256, 0, stream>>>(x, tok, pos, h);
  half_kernel<<<192, 256, 0, stream>>>(tok, t_h, 49152);

  for (int l = 0; l < 8; ++l) {
    ln_half_kernel<<<8192, 256, 0, stream>>>(h, ln1g + l * 768, ln1b + l * 768, a_h);
    thalf_kernel<<<dim3(72, 24), 256, 0, stream>>>(Wqkv + (long)l * 768 * 2304, w_h, 768, 2304);
    gemm_f16<4><<<64 * 18, 256, 0, stream>>>(a_h, w_h, 8192, 2304, 768, bqkv + l * 2304,
                                             nullptr, nullptr, nullptr, Qb, Kbuf, Vbuf);
    attn_kernel<<<768, 256, 0, stream>>>(Qb, Kbuf, Vbuf, o_h);
    thalf_kernel<<<dim3(24, 24), 256, 0, stream>>>(Wproj + (long)l * 768 * 768, w_h, 768, 768);
    gemm_f16<1><<<64 * 6, 256, 0, stream>>>(o_h, w_h, 8192, 768, 768, bproj + l * 768,
                                            h, h, nullptr, nullptr, nullptr, nullptr);
    ln_half_kernel<<<8192, 256, 0, stream>>>(h, ln2g + l * 768, ln2b + l * 768, a_h);
    thalf_kernel<<<dim3(96, 24), 256, 0, stream>>>(Wff1 + (long)l * 768 * 3072, w_h, 768, 3072);
    gemm_f16<2><<<64 * 24, 256, 0, stream>>>(a_h, w_h, 8192, 3072, 768, bff1 + l * 3072,
                                             nullptr, nullptr, f_h, nullptr, nullptr, nullptr);
    thalf_kernel<<<dim3(24, 96), 256, 0, stream>>>(Wff2 + (long)l * 3072 * 768, w_h, 3072, 768);
    gemm_f16<1><<<64 * 6, 256, 0, stream>>>(f_h, w_h, 8192, 768, 3072, bff2 + l * 768,
                                            h, h, nullptr, nullptr, nullptr, nullptr);
  }
  ln_half_kernel<<<8192, 256, 0, stream>>>(h, lnfg, lnfb, a_h);
  gemm_f16<3><<<64 * 2, 256, 0, stream>>>(a_h, t_h, 8192, 256, 768, nullptr,
                                          nullptr, out, nullptr, nullptr, nullptr, nullptr);
}